// Round 9
// baseline (989.101 us; speedup 1.0000x reference)
//
#include <hip/hip_runtime.h>
#include <math.h>

#define NNODES 358
#define NN2 (358*358)
#define DIM 96
#define PP 72
#define ND 64
#define NB 8
#define NH 4
#define SEQ (NB*NNODES)

// ---- workspace layout (float offsets) ----
#define WS_WT2   0            // 4*96*72: per-head transposed in_proj (k-major [h][k][72])
#define WS_WBAR  27648        // 96
#define WS_BBAR  27744        // 1
#define WS_POSB  27748        // 96: column-mean of pos
#define WS_PRM   27848        // SEQ*96
#define WS_DEA   302792       // SEQ*64
#define WS_DEB   486088       // SEQ*64  (ends 669384)

__device__ __forceinline__ float gelu_f(float y) {
  return 0.5f*y*(1.0f+erff(y*0.70710678118654752440f));
}

// -------- per-wave register softmax+top-10 over one row of 358 logits -------
__device__ __forceinline__ void wave_topk_row(const float* __restrict__ lgr,
                                              float* __restrict__ orow)
{
  int lane = threadIdx.x & 63;
  float vals[6];
  #pragma unroll
  for (int j = 0; j < 6; ++j) {
    int m = lane + 64*j;
    vals[j] = (m < NNODES) ? lgr[m] : -1e30f;
  }
  float mx = vals[0];
  #pragma unroll
  for (int j = 1; j < 6; ++j) mx = fmaxf(mx, vals[j]);
  #pragma unroll
  for (int o = 32; o; o >>= 1) mx = fmaxf(mx, __shfl_xor(mx, o, 64));
  float M = mx;
  float ls = 0.0f;
  #pragma unroll
  for (int j = 0; j < 6; ++j) ls += __expf(vals[j] - M);   // OOB -> exp(-big)=0
  #pragma unroll
  for (int o = 32; o; o >>= 1) ls += __shfl_xor(ls, o, 64);
  float invS = 1.0f/ls;
  float outv[6] = {0.f, 0.f, 0.f, 0.f, 0.f, 0.f};
  float ss = 0.0f;
  for (int it = 0; it < 10; ++it) {
    float v = -1e30f; int idx = 0x7fffffff;
    #pragma unroll
    for (int j = 0; j < 6; ++j) {
      if (vals[j] > v) { v = vals[j]; idx = lane + 64*j; }
    }
    #pragma unroll
    for (int o = 1; o < 64; o <<= 1) {
      float ov = __shfl_xor(v, o, 64);
      int oi = __shfl_xor(idx, o, 64);
      if (ov > v || (ov == v && oi < idx)) { v = ov; idx = oi; }
    }
    ss += __expf(v - M);
    #pragma unroll
    for (int j = 0; j < 6; ++j)
      if (lane + 64*j == idx) { outv[j] = __expf(v - M); vals[j] = -1e30f; }
  }
  float dn = 1.0f/(ss*invS + 1e-8f);
  #pragma unroll
  for (int j = 0; j < 6; ++j) {
    int m = lane + 64*j;
    if (m < NNODES) orow[m] = outv[j]*invS*dn;
  }
}

// ---------------------------------------------------------------- k0: setup
__global__ void k0_setup(const float* __restrict__ wi, const float* __restrict__ wo,
                         const float* __restrict__ bo, const float* __restrict__ pos,
                         float* __restrict__ ws)
{
  int t = threadIdx.x;
  for (int idx = t; idx < 4*96*72; idx += 256) {
    int h = idx / (96*72);
    int r = idx - h*96*72;
    int k = r / 72;
    int gc = r - k*72;
    int g = gc / 24, c = gc - g*24;
    ws[WS_WT2 + idx] = wi[(size_t)(g*96 + h*24 + c)*96 + k];
  }
  if (t < 96) {
    float sm = 0.0f;
    for (int d = 0; d < 96; ++d) sm += wo[d*96 + t];
    ws[WS_WBAR + t] = sm*(1.0f/96.0f);
    float ps = 0.0f;
    for (int p = 0; p < PP; ++p) ps += pos[p*96 + t];
    ws[WS_POSB + t] = ps*(1.0f/72.0f);
  }
  if (t == 0) {
    float sm = 0.0f;
    for (int d = 0; d < 96; ++d) sm += bo[d];
    ws[WS_BBAR] = sm*(1.0f/96.0f);
  }
}

// --------------------------------------------------- k1: static adjacencies
#define K1_RPB 4
#define K1_BPH 90   // ceil(358/4)

__global__ void __launch_bounds__(256)
k1_static4(const float* __restrict__ le1, const float* __restrict__ le2,
           const float* __restrict__ ge1, const float* __restrict__ ge2,
           const float* __restrict__ temp, float* __restrict__ outstat)
{
  __shared__ float e1s[K1_RPB][64];
  __shared__ float lg[K1_RPB][NNODES];
  int blk = blockIdx.x, t = threadIdx.x;
  int h = blk / K1_BPH;
  int n0 = (blk - h*K1_BPH)*K1_RPB;
  int nrows = NNODES - n0; if (nrows > K1_RPB) nrows = K1_RPB;
  int kd; const float* e2p; float tau;
  if (h < 2) {
    kd = 32;
    e2p = le2 + (size_t)h*32*NNODES;
    tau = fminf(fmaxf(temp[h]*2.0f, 0.1f), 5.0f);
  } else {
    kd = 64;
    e2p = ge2 + (size_t)(h-2)*64*NNODES;
    tau = fminf(fmaxf(temp[h]*0.5f, 0.1f), 2.0f);
  }
  {
    int r = t >> 6, k = t & 63;
    float v = 0.0f;
    if (r < nrows && k < kd)
      v = (h < 2) ? le1[((size_t)h*NNODES + n0 + r)*32 + k]
                  : ge1[((size_t)(h-2)*NNODES + n0 + r)*64 + k];
    e1s[r][k] = v;
  }
  __syncthreads();
  float itau = 1.0f/tau;
  for (int m = t; m < NNODES; m += 256) {
    float s0=0.f, s1=0.f, s2=0.f, s3=0.f;
    for (int k = 0; k < kd; ++k) {
      float ev = e2p[k*NNODES + m];
      s0 += e1s[0][k]*ev;
      s1 += e1s[1][k]*ev;
      s2 += e1s[2][k]*ev;
      s3 += e1s[3][k]*ev;
    }
    lg[0][m] = fmaxf(s0, 0.0f)*itau;
    lg[1][m] = fmaxf(s1, 0.0f)*itau;
    lg[2][m] = fmaxf(s2, 0.0f)*itau;
    lg[3][m] = fmaxf(s3, 0.0f)*itau;
  }
  __syncthreads();
  int wv = t >> 6;
  if (wv < nrows)
    wave_topk_row(lg[wv], outstat + ((size_t)h*NNODES + n0 + wv)*NNODES);
}

// --------------------------------------- k2a_fused: per-s attention (4 heads)
//                                          + node epilogue + dynamic encoder
// Round-9: LDS-read-BW roofline fix. Measured: 8.6 MB LDS reads/block =
// 86 B/cyc/CU = the ds_read_b128 ceiling -> kernel is LDS-BW-bound.
// LDS bytes per GEMM phase ~ (1/R + 1/C) of the register tile:
//  - QKV 3x4 -> 4x6 (216 thr): 1.16 -> 0.83 MB/head, W reads spread 12 banks
//  - S 2x4 -> 4x4 (324 thr): 373 -> 248 KB/head
//  - PV 1x4 -> 2x4 (216 thr): V re-read 72x -> 36x, 622 -> 372 KB/head
//  - softmax p1+p2 merged via 4-lane shfl groups (one fewer barrier/head)
// Config stays (512,4): cap 64, 2 blocks/CU = 16 waves (r7-proven).
#define A_XS    0      // X' 72x100 (QKV input); after head loop: O 72x100
#define A_WH    7200   // W_h 96x72 k-major (6912); aliased by S after QKV
#define A_SS    7200   // S 72x76 (alias of A_WH)
#define A_WB    7200   // --- tail scratch (S dead) ---
#define A_LIMP  7296
#define A_IMP   7368
#define A_WSUM  7440
#define A_NB    7536
#define A_NR    7632
#define A_H1    7728
#define A_G1    7856
#define A_H2    7984   // ends 8048
#define A_PART  12672  // 512 (in W-region tail beyond S's 5472)
#define A_PART2 13184  // 72 row sums
#define A_QH    14112  // Q 72x28
#define A_KT    16128  // K^T 24x76
#define A_VT    17952  // V^T 24x76
#define A_PRM   19776  // 96 (survives head loop)
#define A_TOT   19872

__global__ void __launch_bounds__(512, 4)
k2a_fused(const float* __restrict__ pf, const float* __restrict__ pos,
          const float* __restrict__ inb, float* __restrict__ ws,
          const float* __restrict__ wo, const float* __restrict__ bo,
          const float* __restrict__ tng, const float* __restrict__ tnb,
          const float* __restrict__ dw1, const float* __restrict__ db1,
          const float* __restrict__ dg1, const float* __restrict__ dlb1,
          const float* __restrict__ dw2, const float* __restrict__ db2,
          const float* __restrict__ dg2, const float* __restrict__ dlb2)
{
  __shared__ __align__(16) float L[A_TOT];
  int t = threadIdx.x;
  size_t s = blockIdx.x;
  const float* prp = pf + s*(PP*DIM);
  // ---- X = pf + pos -> LDS (stride 100), single fused pass
  for (int idx = t; idx < 1728; idx += 512) {
    float4 v = ((const float4*)prp)[idx];
    float4 q = ((const float4*)pos)[idx];
    v.x += q.x; v.y += q.y; v.z += q.z; v.w += q.w;
    int p = idx / 24, e4 = idx - p*24;
    *(float4*)&L[A_XS + p*100 + e4*4] = v;
  }
  __syncthreads();
  if (t < DIM) {   // pf.mean over P == colmean(X') - colmean(pos)
    float sm = 0.0f;
    for (int p = 0; p < PP; ++p) sm += L[A_XS + p*100 + t];
    sm = sm*(1.0f/72.0f) - ws[WS_POSB + t];
    L[A_PRM + t] = sm;
    ws[WS_PRM + s*DIM + t] = sm;       // k6 needs it
  }
  const float SC = 0.20412414523193150f;  // 1/sqrt(24)
  // per-head PV output: 2 rows x 4 cols per thread = 2 float4 per head (named)
  float4 o0a, o0b, o1a, o1b, o2a, o2b, o3a, o3b;
  #pragma unroll
  for (int h = 0; h < NH; ++h) {
    __syncthreads();   // h=0: X/prm ready; h>0: prev PV done reading S (W aliases S)
    __builtin_amdgcn_sched_barrier(0);
    // ---- stage W_h (k-major [96][72]) into LDS: linear float4 copy
    const float4* wsrc = (const float4*)(ws + WS_WT2 + (size_t)h*6912);
    for (int idx = t; idx < 1728; idx += 512)
      *(float4*)&L[A_WH + idx*4] = wsrc[idx];
    __builtin_amdgcn_sched_barrier(0);
    __syncthreads();
    // ---- QKV: 18 row-tiles(4) x 12 col-tiles(6) = 216 threads, serial k=96
    if (t < 216) {
      int rt = t / 12, ct = t - rt*12;
      int p0 = rt*4, gc0 = ct*6;
      float acc[4][6];
      #pragma unroll
      for (int a = 0; a < 4; ++a)
        #pragma unroll
        for (int c = 0; c < 6; ++c) acc[a][c] = 0.0f;
      for (int k0 = 0; k0 < 96; k0 += 4) {
        float4 xv[4];
        #pragma unroll
        for (int a = 0; a < 4; ++a) xv[a] = *(const float4*)&L[A_XS + (p0+a)*100 + k0];
        const float* wr = &L[A_WH + k0*72 + gc0];
        #pragma unroll
        for (int kk = 0; kk < 4; ++kk) {
          float2 w01 = *(const float2*)(wr + kk*72);
          float2 w23 = *(const float2*)(wr + kk*72 + 2);
          float2 w45 = *(const float2*)(wr + kk*72 + 4);
          float wv[6] = {w01.x, w01.y, w23.x, w23.y, w45.x, w45.y};
          #pragma unroll
          for (int a = 0; a < 4; ++a) {
            float xa = ((const float*)&xv[a])[kk];
            #pragma unroll
            for (int c = 0; c < 6; ++c) acc[a][c] += xa*wv[c];
          }
        }
      }
      int g = gc0 / 24;           // 6 | 24: tile never straddles q/k/v groups
      int ch = gc0 - g*24;
      #pragma unroll
      for (int c = 0; c < 6; ++c) {
        float bias = inb[g*96 + h*24 + ch + c];
        #pragma unroll
        for (int a = 0; a < 4; ++a) {
          float v = acc[a][c] + bias;
          int p = p0 + a;
          if (g == 0)      L[A_QH + p*28 + ch + c] = v*SC;
          else if (g == 1) L[A_KT + (ch+c)*76 + p] = v;
          else             L[A_VT + (ch+c)*76 + p] = v;
        }
      }
    }
    __syncthreads();                  // W dead from here: S aliases it
    if (t < 324) {                    // S = q k^T: 18 p-tiles(4) x 18 j-tiles(4)
      int pt = t / 18, jt = t - pt*18;
      int p0 = pt*4, j0 = jt*4;
      float acc[4][4];
      #pragma unroll
      for (int a = 0; a < 4; ++a)
        { acc[a][0]=0.f; acc[a][1]=0.f; acc[a][2]=0.f; acc[a][3]=0.f; }
      #pragma unroll
      for (int d0 = 0; d0 < 24; d0 += 4) {
        float4 q[4];
        #pragma unroll
        for (int a = 0; a < 4; ++a) q[a] = *(const float4*)&L[A_QH + (p0+a)*28 + d0];
        #pragma unroll
        for (int dd = 0; dd < 4; ++dd) {
          float4 kv = *(const float4*)&L[A_KT + (d0+dd)*76 + j0];
          #pragma unroll
          for (int a = 0; a < 4; ++a) {
            float qa = ((const float*)&q[a])[dd];
            acc[a][0] += qa*kv.x;
            acc[a][1] += qa*kv.y;
            acc[a][2] += qa*kv.z;
            acc[a][3] += qa*kv.w;
          }
        }
      }
      #pragma unroll
      for (int a = 0; a < 4; ++a)
        *(float4*)&L[A_SS + (p0+a)*76 + j0] =
          make_float4(acc[a][0], acc[a][1], acc[a][2], acc[a][3]);
    }
    __syncthreads();
    if (t < 288) {   // merged softmax: 72 rows x 4 segs; groups of 4 lanes/row
      int r = t >> 2, sg = t & 3, j0 = sg*18;
      float* row = &L[A_SS + r*76];
      float mx = row[j0];
      for (int j = j0+1; j < j0+18; ++j) mx = fmaxf(mx, row[j]);
      mx = fmaxf(mx, __shfl_xor(mx, 1, 64));
      mx = fmaxf(mx, __shfl_xor(mx, 2, 64));      // full row max in all 4 lanes
      float sm = 0.0f;
      for (int j = j0; j < j0+18; ++j) { float e = __expf(row[j]-mx); row[j] = e; sm += e; }
      sm += __shfl_xor(sm, 1, 64);
      sm += __shfl_xor(sm, 2, 64);                // full row sum
      if (sg == 0) L[A_PART2 + r] = sm;
    }
    __syncthreads();
    if (t < 216) {                    // PV: 2 rows x 4 cols (36 x 6 tiles)
      int pt = t / 6, dt = t - (t/6)*6;
      int p0 = pt*2, d0 = dt*4;
      float inv0 = 1.0f/L[A_PART2 + p0];
      float inv1 = 1.0f/L[A_PART2 + p0 + 1];
      float acc[2][4];
      #pragma unroll
      for (int a = 0; a < 2; ++a)
        { acc[a][0]=0.f; acc[a][1]=0.f; acc[a][2]=0.f; acc[a][3]=0.f; }
      for (int j0 = 0; j0 < 72; j0 += 4) {
        float4 pv0 = *(const float4*)&L[A_SS + p0*76 + j0];
        float4 pv1 = *(const float4*)&L[A_SS + (p0+1)*76 + j0];
        #pragma unroll
        for (int dd = 0; dd < 4; ++dd) {
          float4 vv = *(const float4*)&L[A_VT + (d0+dd)*76 + j0];
          acc[0][dd] += pv0.x*vv.x + pv0.y*vv.y + pv0.z*vv.z + pv0.w*vv.w;
          acc[1][dd] += pv1.x*vv.x + pv1.y*vv.y + pv1.z*vv.z + pv1.w*vv.w;
        }
      }
      float4 oa = make_float4(acc[0][0]*inv0, acc[0][1]*inv0, acc[0][2]*inv0, acc[0][3]*inv0);
      float4 ob = make_float4(acc[1][0]*inv1, acc[1][1]*inv1, acc[1][2]*inv1, acc[1][3]*inv1);
      if (h == 0)      { o0a = oa; o0b = ob; }
      else if (h == 1) { o1a = oa; o1b = ob; }
      else if (h == 2) { o2a = oa; o2b = ob; }
      else             { o3a = oa; o3b = ob; }
    }
  }
  // ---- node epilogue; O overwrites dead X region, scratch aliases dead S
  __syncthreads();                    // last PV done reading S before WB/O writes
  if (t < 216) {
    int pt = t / 6, dt = t - (t/6)*6;
    int p0 = pt*2, d0 = dt*4;
    *(float4*)&L[A_XS + p0*100     +  0 + d0] = o0a;
    *(float4*)&L[A_XS + (p0+1)*100 +  0 + d0] = o0b;
    *(float4*)&L[A_XS + p0*100     + 24 + d0] = o1a;
    *(float4*)&L[A_XS + (p0+1)*100 + 24 + d0] = o1b;
    *(float4*)&L[A_XS + p0*100     + 48 + d0] = o2a;
    *(float4*)&L[A_XS + (p0+1)*100 + 48 + d0] = o2b;
    *(float4*)&L[A_XS + p0*100     + 72 + d0] = o3a;
    *(float4*)&L[A_XS + (p0+1)*100 + 72 + d0] = o3b;
  }
  if (t < 96) L[A_WB + t] = ws[WS_WBAR + t];
  __syncthreads();
  if (t < 288) {   // limp partials: att.mean(-1) == O . wbar (+bbar in combine)
    int r = t >> 2, sg = t & 3, e0 = sg*24;
    float sm = 0.0f;
    for (int e = e0; e < e0+24; ++e) sm += L[A_XS + r*100 + e]*L[A_WB + e];
    L[A_PART + t] = sm;
  }
  __syncthreads();
  if (t < 72) {
    int rb = t << 2;
    L[A_LIMP + t] = L[A_PART+rb]+L[A_PART+rb+1]+L[A_PART+rb+2]+L[A_PART+rb+3]
                  + ws[WS_BBAR];
  }
  __syncthreads();
  if (t < 72) {    // patch-importance softmax (small, serial)
    float mx = L[A_LIMP];
    for (int j = 1; j < 72; ++j) mx = fmaxf(mx, L[A_LIMP+j]);
    float sm = 0.0f;
    for (int j = 0; j < 72; ++j) sm += __expf(L[A_LIMP+j]-mx);
    L[A_IMP + t] = __expf(L[A_LIMP+t]-mx)/sm;
  }
  __syncthreads();
  if (t < 384) {   // wsum partials: (O * imp).sum over p
    int c = t >> 2, sg = t & 3, p0 = sg*18;
    float sm = 0.0f;
    for (int p = p0; p < p0+18; ++p) sm += L[A_IMP+p]*L[A_XS + p*100 + c];
    L[A_PART + t] = sm;
  }
  __syncthreads();
  if (t < 96) {
    int rb = t << 2;
    L[A_WSUM + t] = L[A_PART+rb]+L[A_PART+rb+1]+L[A_PART+rb+2]+L[A_PART+rb+3];
  }
  __syncthreads();
  if (t < 384) {   // NB partials: out_proj
    int c = t >> 2, sg = t & 3, e0 = sg*24;
    float sm = 0.0f;
    for (int e = e0; e < e0+24; ++e) sm += L[A_WSUM+e]*wo[c*96 + e];
    L[A_PART + t] = sm;
  }
  __syncthreads();
  if (t < 96) {
    int rb = t << 2;
    L[A_NB + t] = L[A_PART+rb]+L[A_PART+rb+1]+L[A_PART+rb+2]+L[A_PART+rb+3]
                + bo[t] + L[A_PRM + t];
  }
  __syncthreads();
  if (t < 96) {    // token LN
    float mean = 0.0f;
    for (int e = 0; e < 96; ++e) mean += L[A_NB+e];
    mean *= (1.0f/96.0f);
    float var = 0.0f;
    for (int e = 0; e < 96; ++e) { float d = L[A_NB+e]-mean; var += d*d; }
    var *= (1.0f/96.0f);
    L[A_NR + t] = (L[A_NB+t]-mean)*rsqrtf(var+1e-5f)*tng[t] + tnb[t];
  }
  __syncthreads();
  {                // H1 partials: de_w1 (128 x 96) — 128 cols x 4 segs(24) = 512
    int c = t >> 2, sg = t & 3, k0 = sg*24;
    float sm = 0.0f;
    for (int k = k0; k < k0+24; ++k) sm += L[A_NR+k]*dw1[c*96 + k];
    L[A_PART + t] = sm;
  }
  __syncthreads();
  if (t < 128) {
    int rb = t << 2;
    L[A_H1 + t] = L[A_PART+rb]+L[A_PART+rb+1]+L[A_PART+rb+2]+L[A_PART+rb+3] + db1[t];
  }
  __syncthreads();
  if (t < 128) {   // LN + GELU
    float mean = 0.0f; for (int e = 0; e < 128; ++e) mean += L[A_H1+e];
    mean *= (1.0f/128.0f);
    float var = 0.0f; for (int e = 0; e < 128; ++e) { float d = L[A_H1+e]-mean; var += d*d; }
    var *= (1.0f/128.0f);
    float y = (L[A_H1+t]-mean)*rsqrtf(var+1e-5f)*dg1[t] + dlb1[t];
    L[A_G1 + t] = gelu_f(y);
  }
  __syncthreads();
  if (t < 256) {   // H2 partials: de_w2 (64 x 128) — 64 cols x 4 segs(32)
    int c = t >> 2, sg = t & 3, k0 = sg*32;
    float sm = 0.0f;
    for (int k = k0; k < k0+32; ++k) sm += L[A_G1+k]*dw2[c*128 + k];
    L[A_PART + t] = sm;
  }
  __syncthreads();
  if (t < 64) {
    int rb = t << 2;
    L[A_H2 + t] = L[A_PART+rb]+L[A_PART+rb+1]+L[A_PART+rb+2]+L[A_PART+rb+3] + db2[t];
  }
  __syncthreads();
  if (t < 64) {
    float mean = 0.0f; for (int e = 0; e < 64; ++e) mean += L[A_H2+e];
    mean *= (1.0f/64.0f);
    float var = 0.0f; for (int e = 0; e < 64; ++e) { float d = L[A_H2+e]-mean; var += d*d; }
    var *= (1.0f/64.0f);
    ws[WS_DEA + s*ND + t] = (L[A_H2+t]-mean)*rsqrtf(var+1e-5f)*dg2[t] + dlb2[t];
  }
}

// --------------------------------------------------------- k4: one GNN layer
#define K4_RPB 4
#define K4_BPB 90   // ceil(358/4)

__global__ void __launch_bounds__(256)
k4_gnn(float* __restrict__ ws, int inoff, int outoff,
       const float* __restrict__ w, const float* __restrict__ bb,
       const float* __restrict__ g, const float* __restrict__ beta)
{
  __shared__ __align__(16) float nrow[K4_RPB][64];
  __shared__ float lg[K4_RPB][NNODES];
  __shared__ float pbl[K4_RPB][NNODES];
  __shared__ float aggp[4][K4_RPB][64];
  __shared__ float aggb[K4_RPB][64];
  __shared__ float prj[K4_RPB][64];
  int blk = blockIdx.x, t = threadIdx.x;
  int b = blk / K4_BPB;
  int n0 = (blk - b*K4_BPB)*K4_RPB;
  int nrows = NNODES - n0; if (nrows > K4_RPB) nrows = K4_RPB;
  {
    int r = t >> 6, d = t & 63;
    nrow[r][d] = (r < nrows)
      ? ws[inoff + ((size_t)(b*NNODES) + n0 + r)*ND + d] : 0.0f;
  }
  __syncthreads();
  const float* deb = ws + inoff + (size_t)b*NNODES*ND;
  for (int m = t; m < NNODES; m += 256) {
    const float* dr = deb + (size_t)m*ND;
    float s0=0.f, s1=0.f, s2=0.f, s3=0.f;
    #pragma unroll
    for (int d0 = 0; d0 < 64; d0 += 4) {
      float4 dv = *(const float4*)&dr[d0];
      float4 n0v = *(const float4*)&nrow[0][d0];
      float4 n1v = *(const float4*)&nrow[1][d0];
      float4 n2v = *(const float4*)&nrow[2][d0];
      float4 n3v = *(const float4*)&nrow[3][d0];
      s0 += dv.x*n0v.x + dv.y*n0v.y + dv.z*n0v.z + dv.w*n0v.w;
      s1 += dv.x*n1v.x + dv.y*n1v.y + dv.z*n1v.z + dv.w*n1v.w;
      s2 += dv.x*n2v.x + dv.y*n2v.y + dv.z*n2v.z + dv.w*n2v.w;
      s3 += dv.x*n3v.x + dv.y*n3v.y + dv.z*n3v.z + dv.w*n3v.w;
    }
    lg[0][m] = s0*5.0f;
    lg[1][m] = s1*5.0f;
    lg[2][m] = s2*5.0f;
    lg[3][m] = s3*5.0f;
  }
  __syncthreads();
  int wv = t >> 6, lane = t & 63;
  {  // per-wave register softmax of row wv -> pbl[wv][.] (normalized)
    const float* lgr = lg[wv];
    float vals[6];
    #pragma unroll
    for (int j = 0; j < 6; ++j) {
      int m = lane + 64*j;
      vals[j] = (m < NNODES) ? lgr[m] : -1e30f;
    }
    float mx = vals[0];
    #pragma unroll
    for (int j = 1; j < 6; ++j) mx = fmaxf(mx, vals[j]);
    #pragma unroll
    for (int o = 32; o; o >>= 1) mx = fmaxf(mx, __shfl_xor(mx, o, 64));
    float M = mx;
    float ls = 0.0f;
    #pragma unroll
    for (int j = 0; j < 6; ++j) ls += __expf(vals[j] - M);
    #pragma unroll
    for (int o = 32; o; o >>= 1) ls += __shfl_xor(ls, o, 64);
    float inv = 1.0f/ls;
    #pragma unroll
    for (int j = 0; j < 6; ++j) {
      int m = lane + 64*j;
      if (m < NNODES) pbl[wv][m] = __expf(vals[j] - M)*inv;
    }
  }
  __syncthreads();
  {  // agg partials: wave wv handles m == wv (mod 4); d = lane (coalesced)
    int d = lane;
    float a0=0.f, a1=0.f, a2=0.f, a3=0.f;
    for (int m = wv; m < NNODES; m += 4) {
      float dv = deb[(size_t)m*ND + d];
      a0 += pbl[0][m]*dv;
      a1 += pbl[1][m]*dv;
      a2 += pbl[2][m]*dv;
      a3 += pbl[3][m]*dv;
    }
    aggp[wv][0][d] = a0;
    aggp[wv][1][d] = a1;
    aggp[wv][2][d] = a2;
    aggp[wv][3][d] = a3;
  }
  __syncthreads();
  {
    int r = t >> 6, d = t & 63;
    aggb[r][d] = aggp[0][r][d]+aggp[1][r][d]+aggp[2][r][d]+aggp[3][r][d];
  }
  __syncthreads();
  {  // proj: 4 rows x 64 cols = 256 threads
    int r = t >> 6, c = t & 63;
    float sm = 0.0f;
    for (int d = 0; d < 64; ++d) sm += aggb[r][d]*w[c*64 + d];
    prj[r][c] = sm + bb[c];
  }
  __syncthreads();
  {  // LN + GELU + residual, 4 rows in parallel
    int r = t >> 6, c = t & 63;
    float mean = 0.0f; for (int e = 0; e < 64; ++e) mean += prj[r][e];
    mean *= (1.0f/64.0f);
    float var = 0.0f; for (int e = 0; e < 64; ++e) { float d = prj[r][e]-mean; var += d*d; }
    var *= (1.0f/64.0f);
    float y = (prj[r][c]-mean)*rsqrtf(var+1e-5f)*g[c] + beta[c];
    if (r < nrows)
      ws[outoff + ((size_t)(b*NNODES) + n0 + r)*ND + c] = gelu_f(y) + nrow[r][c];
  }
}

// ----------------------------------------------- k5: dynamic adj + top-k
#define K5_RPB 4
#define K5_BPH 90   // ceil(358/4)

__global__ void __launch_bounds__(256)
k5_dyn4(const float* __restrict__ ws, const float* __restrict__ se2,
        const float* __restrict__ temp, float* __restrict__ outdyn)
{
  __shared__ float den[K5_RPB][64];
  __shared__ float lg[K5_RPB][NNODES];
  int blk = blockIdx.x, t = threadIdx.x;
  int bh = blk / K5_BPH;              // 0..31  (b*4 + h)
  int n0 = (blk - bh*K5_BPH)*K5_RPB;  // 0,4,...,356
  int h = bh & 3, b = bh >> 2;
  int nrows = NNODES - n0; if (nrows > K5_RPB) nrows = K5_RPB;
  if (t < K5_RPB*64) {
    int r = t >> 6, d = t & 63;
    den[r][d] = (r < nrows)
      ? ws[WS_DEA + ((size_t)(b*NNODES) + n0 + r)*ND + d] : 0.0f;
  }
  __syncthreads();
  float tau = fminf(fmaxf(temp[h], 0.1f), 2.0f);
  const float* sp = se2 + (size_t)h*64*NNODES;
  float itau = 1.0f/tau;
  for (int m = t; m < NNODES; m += 256) {
    float s0=0.f, s1=0.f, s2=0.f, s3=0.f;
    for (int d = 0; d < 64; ++d) {
      float wv_ = sp[d*NNODES + m];
      s0 += den[0][d]*wv_;
      s1 += den[1][d]*wv_;
      s2 += den[2][d]*wv_;
      s3 += den[3][d]*wv_;
    }
    lg[0][m] = fmaxf(s0, 0.0f)*itau;
    lg[1][m] = fmaxf(s1, 0.0f)*itau;
    lg[2][m] = fmaxf(s2, 0.0f)*itau;
    lg[3][m] = fmaxf(s3, 0.0f)*itau;
  }
  __syncthreads();
  int wv = t >> 6;
  if (wv < nrows)
    wave_topk_row(lg[wv], outdyn + ((size_t)bh*NNODES + n0 + wv)*NNODES);
}

// ---------------------------------- k6: fusion + edge encoder + final adj
__global__ void __launch_bounds__(256)
k6_fuse(const float* __restrict__ ws, const float* __restrict__ outstat,
        const float* __restrict__ outdyn,
        const float* __restrict__ gfw, const float* __restrict__ gfb,
        const float* __restrict__ ew1, const float* __restrict__ eb1,
        const float* __restrict__ elg, const float* __restrict__ elb,
        const float* __restrict__ ew2, const float* __restrict__ eb2,
        const float* __restrict__ ew3, const float* __restrict__ eb3,
        float* __restrict__ outfin)
{
  __shared__ float sw1[64], sb1[16], slg[16], slb[16], sw2[128], sb2[8], sw3[8], sb3[1], sfw[4];
  int blk = blockIdx.x, t = threadIdx.x;
  int b = blk / NNODES, n = blk - b*NNODES;
  if (t < 64)  sw1[t] = ew1[t];
  if (t < 16)  { sb1[t] = eb1[t]; slg[t] = elg[t]; slb[t] = elb[t]; }
  if (t < 128) sw2[t] = ew2[t];
  if (t < 8)   { sb2[t] = eb2[t]; sw3[t] = ew3[t]; }
  if (t == 0)  sb3[0] = eb3[0];
  if (t < 4) {
    const float* pm = ws + WS_PRM + (size_t)blk*DIM;
    float sm = gfb[t];
    for (int e = 0; e < DIM; ++e) sm += pm[e]*gfw[t*DIM + e];
    sfw[t] = 1.0f/(1.0f+__expf(-sm));
  }
  __syncthreads();
  size_t srow = (size_t)n*NNODES;
  for (int m = t; m < NNODES; m += 256) {
    float fu[4]; float mn = 0.0f;
    #pragma unroll
    for (int hh = 0; hh < 4; ++hh) {
      float sv = outstat[(size_t)hh*NN2 + srow + m];
      float dv = outdyn[((size_t)(b*4+hh)*NNODES + n)*NNODES + m];
      float f = (1.0f - sfw[hh])*sv + sfw[hh]*dv;
      fu[hh] = f; mn += f;
    }
    mn *= 0.25f;
    float h1[16]; float m1 = 0.0f;
    #pragma unroll
    for (int j = 0; j < 16; ++j) {
      float sm = sb1[j];
      #pragma unroll
      for (int c = 0; c < 4; ++c) sm += fu[c]*sw1[j*4+c];
      h1[j] = sm; m1 += sm;
    }
    m1 *= (1.0f/16.0f);
    float v1 = 0.0f;
    #pragma unroll
    for (int j = 0; j < 16; ++j) { float d = h1[j]-m1; v1 += d*d; }
    float is1 = rsqrtf(v1*(1.0f/16.0f) + 1e-5f);
    #pragma unroll
    for (int j = 0; j < 16; ++j) h1[j] = gelu_f((h1[j]-m1)*is1*slg[j] + slb[j]);
    float h2[8];
    #pragma unroll
    for (int i = 0; i < 8; ++i) {
      float sm = sb2[i];
      #pragma unroll
      for (int j = 0; j < 16; ++j) sm += h1[j]*sw2[i*16+j];
      h2[i] = gelu_f(sm);
    }
    float ewv = sb3[0];
    #pragma unroll
    for (int i = 0; i < 8; ++i) ewv += h2[i]*sw3[i];
    float fin = (1.0f/(1.0f+__expf(-ewv)))*mn;
    outfin[(size_t)b*NN2 + srow + m] = fin;
  }
}

// ------------------------------------------------------------- launch
extern "C" void kernel_launch(void* const* d_in, const int* in_sizes, int n_in,
                              void* d_out, int out_size, void* d_ws, size_t ws_size,
                              hipStream_t stream)
{
  const float* pf   = (const float*)d_in[0];
  const float* se2  = (const float*)d_in[1];
  const float* le1  = (const float*)d_in[2];
  const float* le2  = (const float*)d_in[3];
  const float* ge1  = (const float*)d_in[4];
  const float* ge2  = (const float*)d_in[5];
  const float* temp = (const float*)d_in[6];
  const float* wi   = (const float*)d_in[7];
  const float* inb  = (const float*)d_in[8];
  const float* wo   = (const float*)d_in[9];
  const float* bo   = (const float*)d_in[10];
  const float* tng  = (const float*)d_in[11];
  const float* tnb  = (const float*)d_in[12];
  const float* dw1  = (const float*)d_in[13];
  const float* db1  = (const float*)d_in[14];
  const float* dg1  = (const float*)d_in[15];
  const float* dlb1 = (const float*)d_in[16];
  const float* dw2  = (const float*)d_in[17];
  const float* db2  = (const float*)d_in[18];
  const float* dg2  = (const float*)d_in[19];
  const float* dlb2 = (const float*)d_in[20];
  const float* pos  = (const float*)d_in[21];
  const float* g1w  = (const float*)d_in[22];
  const float* g1b  = (const float*)d_in[23];
  const float* g1g  = (const float*)d_in[24];
  const float* g1be = (const float*)d_in[25];
  const float* g2w  = (const float*)d_in[26];
  const float* g2b  = (const float*)d_in[27];
  const float* g2g  = (const float*)d_in[28];
  const float* g2be = (const float*)d_in[29];
  const float* gfw  = (const float*)d_in[30];
  const float* gfb  = (const float*)d_in[31];
  const float* ew1  = (const float*)d_in[32];
  const float* eb1  = (const float*)d_in[33];
  const float* elg  = (const float*)d_in[34];
  const float* elb  = (const float*)d_in[35];
  const float* ew2  = (const float*)d_in[36];
  const float* eb2  = (const float*)d_in[37];
  const float* ew3  = (const float*)d_in[38];
  const float* eb3  = (const float*)d_in[39];
  float* ws = (float*)d_ws;
  float* out = (float*)d_out;
  float* outfin  = out;                            // (B,N,N)
  float* outstat = out + (size_t)NB*NN2;           // (H,N,N)
  float* outdyn  = out + (size_t)(NB+NH)*NN2;      // (B,H,N,N)

  k0_setup<<<1, 256, 0, stream>>>(wi, wo, bo, pos, ws);
  k1_static4<<<NH*K1_BPH, 256, 0, stream>>>(le1, le2, ge1, ge2, temp, outstat);
  k2a_fused<<<SEQ, 512, 0, stream>>>(pf, pos, inb, ws, wo, bo, tng, tnb,
                                     dw1, db1, dg1, dlb1, dw2, db2, dg2, dlb2);
  k4_gnn<<<NB*K4_BPB, 256, 0, stream>>>(ws, WS_DEA, WS_DEB, g1w, g1b, g1g, g1be);
  k4_gnn<<<NB*K4_BPB, 256, 0, stream>>>(ws, WS_DEB, WS_DEA, g2w, g2b, g2g, g2be);
  k5_dyn4<<<NB*NH*K5_BPH, 256, 0, stream>>>(ws, se2, temp, outdyn);
  k6_fuse<<<SEQ, 256, 0, stream>>>(ws, outstat, outdyn, gfw, gfb,
                                   ew1, eb1, elg, elb, ew2, eb2, ew3, eb3, outfin);
}

// Round 10
// 941.046 us; speedup vs baseline: 1.0511x; 1.0511x over previous
//
#include <hip/hip_runtime.h>
#include <math.h>

#define NNODES 358
#define NN2 (358*358)
#define DIM 96
#define PP 72
#define ND 64
#define NB 8
#define NH 4
#define SEQ (NB*NNODES)

// ---- workspace layout (float offsets) ----
#define WS_WT2   0            // 4*96*72: per-head transposed in_proj (k-major [h][k][72])
#define WS_WBAR  27648        // 96
#define WS_BBAR  27744        // 1
#define WS_POSB  27748        // 96: column-mean of pos
#define WS_PRM   27848        // SEQ*96
#define WS_DEA   302792       // SEQ*64
#define WS_DEB   486088       // SEQ*64  (ends 669384)

__device__ __forceinline__ float gelu_f(float y) {
  return 0.5f*y*(1.0f+erff(y*0.70710678118654752440f));
}

// -------- per-wave register softmax+top-10 over one row of 358 logits -------
__device__ __forceinline__ void wave_topk_row(const float* __restrict__ lgr,
                                              float* __restrict__ orow)
{
  int lane = threadIdx.x & 63;
  float vals[6];
  #pragma unroll
  for (int j = 0; j < 6; ++j) {
    int m = lane + 64*j;
    vals[j] = (m < NNODES) ? lgr[m] : -1e30f;
  }
  float mx = vals[0];
  #pragma unroll
  for (int j = 1; j < 6; ++j) mx = fmaxf(mx, vals[j]);
  #pragma unroll
  for (int o = 32; o; o >>= 1) mx = fmaxf(mx, __shfl_xor(mx, o, 64));
  float M = mx;
  float ls = 0.0f;
  #pragma unroll
  for (int j = 0; j < 6; ++j) ls += __expf(vals[j] - M);   // OOB -> exp(-big)=0
  #pragma unroll
  for (int o = 32; o; o >>= 1) ls += __shfl_xor(ls, o, 64);
  float invS = 1.0f/ls;
  float outv[6] = {0.f, 0.f, 0.f, 0.f, 0.f, 0.f};
  float ss = 0.0f;
  for (int it = 0; it < 10; ++it) {
    float v = -1e30f; int idx = 0x7fffffff;
    #pragma unroll
    for (int j = 0; j < 6; ++j) {
      if (vals[j] > v) { v = vals[j]; idx = lane + 64*j; }
    }
    #pragma unroll
    for (int o = 1; o < 64; o <<= 1) {
      float ov = __shfl_xor(v, o, 64);
      int oi = __shfl_xor(idx, o, 64);
      if (ov > v || (ov == v && oi < idx)) { v = ov; idx = oi; }
    }
    ss += __expf(v - M);
    #pragma unroll
    for (int j = 0; j < 6; ++j)
      if (lane + 64*j == idx) { outv[j] = __expf(v - M); vals[j] = -1e30f; }
  }
  float dn = 1.0f/(ss*invS + 1e-8f);
  #pragma unroll
  for (int j = 0; j < 6; ++j) {
    int m = lane + 64*j;
    if (m < NNODES) orow[m] = outv[j]*invS*dn;
  }
}

// ---------------------------------------------------------------- k0: setup
__global__ void k0_setup(const float* __restrict__ wi, const float* __restrict__ wo,
                         const float* __restrict__ bo, const float* __restrict__ pos,
                         float* __restrict__ ws)
{
  int t = threadIdx.x;
  for (int idx = t; idx < 4*96*72; idx += 256) {
    int h = idx / (96*72);
    int r = idx - h*96*72;
    int k = r / 72;
    int gc = r - k*72;
    int g = gc / 24, c = gc - g*24;
    ws[WS_WT2 + idx] = wi[(size_t)(g*96 + h*24 + c)*96 + k];
  }
  if (t < 96) {
    float sm = 0.0f;
    for (int d = 0; d < 96; ++d) sm += wo[d*96 + t];
    ws[WS_WBAR + t] = sm*(1.0f/96.0f);
    float ps = 0.0f;
    for (int p = 0; p < PP; ++p) ps += pos[p*96 + t];
    ws[WS_POSB + t] = ps*(1.0f/72.0f);
  }
  if (t == 0) {
    float sm = 0.0f;
    for (int d = 0; d < 96; ++d) sm += bo[d];
    ws[WS_BBAR] = sm*(1.0f/96.0f);
  }
}

// --------------------------------------------------- k1: static adjacencies
#define K1_RPB 4
#define K1_BPH 90   // ceil(358/4)

__global__ void __launch_bounds__(256)
k1_static4(const float* __restrict__ le1, const float* __restrict__ le2,
           const float* __restrict__ ge1, const float* __restrict__ ge2,
           const float* __restrict__ temp, float* __restrict__ outstat)
{
  __shared__ float e1s[K1_RPB][64];
  __shared__ float lg[K1_RPB][NNODES];
  int blk = blockIdx.x, t = threadIdx.x;
  int h = blk / K1_BPH;
  int n0 = (blk - h*K1_BPH)*K1_RPB;
  int nrows = NNODES - n0; if (nrows > K1_RPB) nrows = K1_RPB;
  int kd; const float* e2p; float tau;
  if (h < 2) {
    kd = 32;
    e2p = le2 + (size_t)h*32*NNODES;
    tau = fminf(fmaxf(temp[h]*2.0f, 0.1f), 5.0f);
  } else {
    kd = 64;
    e2p = ge2 + (size_t)(h-2)*64*NNODES;
    tau = fminf(fmaxf(temp[h]*0.5f, 0.1f), 2.0f);
  }
  {
    int r = t >> 6, k = t & 63;
    float v = 0.0f;
    if (r < nrows && k < kd)
      v = (h < 2) ? le1[((size_t)h*NNODES + n0 + r)*32 + k]
                  : ge1[((size_t)(h-2)*NNODES + n0 + r)*64 + k];
    e1s[r][k] = v;
  }
  __syncthreads();
  float itau = 1.0f/tau;
  for (int m = t; m < NNODES; m += 256) {
    float s0=0.f, s1=0.f, s2=0.f, s3=0.f;
    for (int k = 0; k < kd; ++k) {
      float ev = e2p[k*NNODES + m];
      s0 += e1s[0][k]*ev;
      s1 += e1s[1][k]*ev;
      s2 += e1s[2][k]*ev;
      s3 += e1s[3][k]*ev;
    }
    lg[0][m] = fmaxf(s0, 0.0f)*itau;
    lg[1][m] = fmaxf(s1, 0.0f)*itau;
    lg[2][m] = fmaxf(s2, 0.0f)*itau;
    lg[3][m] = fmaxf(s3, 0.0f)*itau;
  }
  __syncthreads();
  int wv = t >> 6;
  if (wv < nrows)
    wave_topk_row(lg[wv], outstat + ((size_t)h*NNODES + n0 + wv)*NNODES);
}

// --------------------------------------- k2a_fused: per-s attention (4 heads)
//                                          + node epilogue + dynamic encoder
// Round-10: exact round-8 structure (QKV 3x4 / S 2x4 / PV 1x4, (512,4) ->
// cap 64, 2 blocks/CU = 16 waves — the measured optimum; r9's bigger tiles
// cut LDS traffic but spilled worse under cap 64, net -57us) + the one
// register-neutral r9 gain: merged single-pass softmax (4-lane shfl groups)
// — one fewer barrier + one fewer 288-thread LDS pass per head.
#define A_XS    0      // X' 72x100 (QKV input); after head loop: O 72x100
#define A_WH    7200   // W_h 96x72 k-major (6912); aliased by S after QKV
#define A_SS    7200   // S 72x76 (alias of A_WH)
#define A_WB    7200   // --- tail scratch (S dead) ---
#define A_LIMP  7296
#define A_IMP   7368
#define A_WSUM  7440
#define A_NB    7536
#define A_NR    7632
#define A_H1    7728
#define A_G1    7856
#define A_H2    7984   // ends 8048
#define A_PART  12672  // 512
#define A_PART2 13184  // 72 row sums
#define A_QH    14112  // Q 72x28
#define A_KT    16128  // K^T 24x76
#define A_VT    17952  // V^T 24x76
#define A_PRM   19776  // 96 (survives head loop)
#define A_TOT   19872

__global__ void __launch_bounds__(512, 4)
k2a_fused(const float* __restrict__ pf, const float* __restrict__ pos,
          const float* __restrict__ inb, float* __restrict__ ws,
          const float* __restrict__ wo, const float* __restrict__ bo,
          const float* __restrict__ tng, const float* __restrict__ tnb,
          const float* __restrict__ dw1, const float* __restrict__ db1,
          const float* __restrict__ dg1, const float* __restrict__ dlb1,
          const float* __restrict__ dw2, const float* __restrict__ db2,
          const float* __restrict__ dg2, const float* __restrict__ dlb2)
{
  __shared__ __align__(16) float L[A_TOT];
  int t = threadIdx.x;
  size_t s = blockIdx.x;
  const float* prp = pf + s*(PP*DIM);
  // ---- X = pf + pos -> LDS (stride 100), single fused pass
  for (int idx = t; idx < 1728; idx += 512) {
    float4 v = ((const float4*)prp)[idx];
    float4 q = ((const float4*)pos)[idx];
    v.x += q.x; v.y += q.y; v.z += q.z; v.w += q.w;
    int p = idx / 24, e4 = idx - p*24;
    *(float4*)&L[A_XS + p*100 + e4*4] = v;
  }
  __syncthreads();
  if (t < DIM) {   // pf.mean over P == colmean(X') - colmean(pos)
    float sm = 0.0f;
    for (int p = 0; p < PP; ++p) sm += L[A_XS + p*100 + t];
    sm = sm*(1.0f/72.0f) - ws[WS_POSB + t];
    L[A_PRM + t] = sm;
    ws[WS_PRM + s*DIM + t] = sm;       // k6 needs it
  }
  const float SC = 0.20412414523193150f;  // 1/sqrt(24)
  float4 oreg0, oreg1, oreg2, oreg3;       // per-head PV output (named -> regs)
  #pragma unroll
  for (int h = 0; h < NH; ++h) {
    __syncthreads();   // h=0: X/prm ready; h>0: prev PV done reading S (W aliases S)
    __builtin_amdgcn_sched_barrier(0);
    // ---- stage W_h (k-major [96][72]) into LDS: linear float4 copy
    const float4* wsrc = (const float4*)(ws + WS_WT2 + (size_t)h*6912);
    for (int idx = t; idx < 1728; idx += 512)
      *(float4*)&L[A_WH + idx*4] = wsrc[idx];
    __builtin_amdgcn_sched_barrier(0);
    __syncthreads();
    // ---- QKV: 24 row-tiles(3) x 18 col-tiles(4) = 432 threads, serial k=96
    if (t < 432) {
      int rt = t / 18, ct = t - rt*18;
      int p0 = rt*3, cc0 = ct*4;
      float acc[3][4];
      #pragma unroll
      for (int a = 0; a < 3; ++a)
        { acc[a][0]=0.f; acc[a][1]=0.f; acc[a][2]=0.f; acc[a][3]=0.f; }
      for (int k0 = 0; k0 < 96; k0 += 4) {
        float4 xv[3];
        #pragma unroll
        for (int a = 0; a < 3; ++a) xv[a] = *(const float4*)&L[A_XS + (p0+a)*100 + k0];
        float4 wv[4];
        #pragma unroll
        for (int kk = 0; kk < 4; ++kk) wv[kk] = *(const float4*)&L[A_WH + (k0+kk)*72 + cc0];
        #pragma unroll
        for (int kk = 0; kk < 4; ++kk) {
          #pragma unroll
          for (int a = 0; a < 3; ++a) {
            float xa = ((const float*)&xv[a])[kk];
            acc[a][0] += xa*wv[kk].x;
            acc[a][1] += xa*wv[kk].y;
            acc[a][2] += xa*wv[kk].z;
            acc[a][3] += xa*wv[kk].w;
          }
        }
      }
      int g = cc0 / 24;           // 0=q,1=k,2=v (tile never straddles: 4|24)
      int ch = cc0 - g*24;
      #pragma unroll
      for (int c = 0; c < 4; ++c) {
        float bias = inb[g*96 + h*24 + ch + c];
        #pragma unroll
        for (int a = 0; a < 3; ++a) {
          float v = acc[a][c] + bias;
          int p = p0 + a;
          if (g == 0)      L[A_QH + p*28 + ch + c] = v*SC;
          else if (g == 1) L[A_KT + (ch+c)*76 + p] = v;
          else             L[A_VT + (ch+c)*76 + p] = v;
        }
      }
    }
    __syncthreads();                  // W dead from here: S aliases it
    for (int tile = t; tile < 648; tile += 512) {  // S = q k^T (2x4 tiles)
      int pt2 = tile / 18, jt2 = tile - pt2*18;
      int p0 = pt2*2, j0 = jt2*4;
      float a0=0,a1=0,a2=0,a3=0, c0=0,c1=0,c2=0,c3=0;
      #pragma unroll
      for (int d0 = 0; d0 < 24; d0 += 4) {
        float4 q0 = *(const float4*)&L[A_QH + p0*28 + d0];
        float4 q1 = *(const float4*)&L[A_QH + (p0+1)*28 + d0];
        #pragma unroll
        for (int dd = 0; dd < 4; ++dd) {
          float4 kv = *(const float4*)&L[A_KT + (d0+dd)*76 + j0];
          float qa = ((const float*)&q0)[dd];
          float qb = ((const float*)&q1)[dd];
          a0 += qa*kv.x; a1 += qa*kv.y; a2 += qa*kv.z; a3 += qa*kv.w;
          c0 += qb*kv.x; c1 += qb*kv.y; c2 += qb*kv.z; c3 += qb*kv.w;
        }
      }
      *(float4*)&L[A_SS + p0*76 + j0]     = make_float4(a0,a1,a2,a3);
      *(float4*)&L[A_SS + (p0+1)*76 + j0] = make_float4(c0,c1,c2,c3);
    }
    __syncthreads();
    if (t < 288) {   // merged softmax: 72 rows x 4 segs; 4-lane shfl groups
      int r = t >> 2, sg = t & 3, j0 = sg*18;
      float* row = &L[A_SS + r*76];
      float mx = row[j0];
      for (int j = j0+1; j < j0+18; ++j) mx = fmaxf(mx, row[j]);
      mx = fmaxf(mx, __shfl_xor(mx, 1, 64));
      mx = fmaxf(mx, __shfl_xor(mx, 2, 64));      // full row max in all 4 lanes
      float sm = 0.0f;
      for (int j = j0; j < j0+18; ++j) { float e = __expf(row[j]-mx); row[j] = e; sm += e; }
      sm += __shfl_xor(sm, 1, 64);
      sm += __shfl_xor(sm, 2, 64);                // full row sum
      if (sg == 0) L[A_PART2 + r] = sm;
    }
    __syncthreads();
    if (t < 432) {                    // PV: 1 row x 4 cols per thread
      int p = t / 6, dt = t - (t/6)*6;
      int d0 = dt*4;
      float inv = 1.0f/L[A_PART2 + p];
      float a0=0,a1=0,a2=0,a3=0;
      for (int j0 = 0; j0 < 72; j0 += 4) {
        float4 pv = *(const float4*)&L[A_SS + p*76 + j0];
        float4 v0 = *(const float4*)&L[A_VT + (d0+0)*76 + j0];
        float4 v1 = *(const float4*)&L[A_VT + (d0+1)*76 + j0];
        float4 v2 = *(const float4*)&L[A_VT + (d0+2)*76 + j0];
        float4 v3 = *(const float4*)&L[A_VT + (d0+3)*76 + j0];
        a0 += pv.x*v0.x + pv.y*v0.y + pv.z*v0.z + pv.w*v0.w;
        a1 += pv.x*v1.x + pv.y*v1.y + pv.z*v1.z + pv.w*v1.w;
        a2 += pv.x*v2.x + pv.y*v2.y + pv.z*v2.z + pv.w*v2.w;
        a3 += pv.x*v3.x + pv.y*v3.y + pv.z*v3.z + pv.w*v3.w;
      }
      float4 ov = make_float4(a0*inv, a1*inv, a2*inv, a3*inv);
      if (h == 0)      oreg0 = ov;
      else if (h == 1) oreg1 = ov;
      else if (h == 2) oreg2 = ov;
      else             oreg3 = ov;
    }
  }
  // ---- node epilogue; O overwrites dead X region, scratch aliases dead S
  __syncthreads();                    // last PV done reading S before WB/O writes
  if (t < 432) {
    int p = t / 6, dt = t - (t/6)*6;
    int d0 = dt*4;
    *(float4*)&L[A_XS + p*100 +  0 + d0] = oreg0;
    *(float4*)&L[A_XS + p*100 + 24 + d0] = oreg1;
    *(float4*)&L[A_XS + p*100 + 48 + d0] = oreg2;
    *(float4*)&L[A_XS + p*100 + 72 + d0] = oreg3;
  }
  if (t < 96) L[A_WB + t] = ws[WS_WBAR + t];
  __syncthreads();
  if (t < 288) {   // limp partials: att.mean(-1) == O . wbar (+bbar in combine)
    int r = t >> 2, sg = t & 3, e0 = sg*24;
    float sm = 0.0f;
    for (int e = e0; e < e0+24; ++e) sm += L[A_XS + r*100 + e]*L[A_WB + e];
    L[A_PART + t] = sm;
  }
  __syncthreads();
  if (t < 72) {
    int rb = t << 2;
    L[A_LIMP + t] = L[A_PART+rb]+L[A_PART+rb+1]+L[A_PART+rb+2]+L[A_PART+rb+3]
                  + ws[WS_BBAR];
  }
  __syncthreads();
  if (t < 72) {    // patch-importance softmax (small, serial)
    float mx = L[A_LIMP];
    for (int j = 1; j < 72; ++j) mx = fmaxf(mx, L[A_LIMP+j]);
    float sm = 0.0f;
    for (int j = 0; j < 72; ++j) sm += __expf(L[A_LIMP+j]-mx);
    L[A_IMP + t] = __expf(L[A_LIMP+t]-mx)/sm;
  }
  __syncthreads();
  if (t < 384) {   // wsum partials: (O * imp).sum over p
    int c = t >> 2, sg = t & 3, p0 = sg*18;
    float sm = 0.0f;
    for (int p = p0; p < p0+18; ++p) sm += L[A_IMP+p]*L[A_XS + p*100 + c];
    L[A_PART + t] = sm;
  }
  __syncthreads();
  if (t < 96) {
    int rb = t << 2;
    L[A_WSUM + t] = L[A_PART+rb]+L[A_PART+rb+1]+L[A_PART+rb+2]+L[A_PART+rb+3];
  }
  __syncthreads();
  if (t < 384) {   // NB partials: out_proj
    int c = t >> 2, sg = t & 3, e0 = sg*24;
    float sm = 0.0f;
    for (int e = e0; e < e0+24; ++e) sm += L[A_WSUM+e]*wo[c*96 + e];
    L[A_PART + t] = sm;
  }
  __syncthreads();
  if (t < 96) {
    int rb = t << 2;
    L[A_NB + t] = L[A_PART+rb]+L[A_PART+rb+1]+L[A_PART+rb+2]+L[A_PART+rb+3]
                + bo[t] + L[A_PRM + t];
  }
  __syncthreads();
  if (t < 96) {    // token LN
    float mean = 0.0f;
    for (int e = 0; e < 96; ++e) mean += L[A_NB+e];
    mean *= (1.0f/96.0f);
    float var = 0.0f;
    for (int e = 0; e < 96; ++e) { float d = L[A_NB+e]-mean; var += d*d; }
    var *= (1.0f/96.0f);
    L[A_NR + t] = (L[A_NB+t]-mean)*rsqrtf(var+1e-5f)*tng[t] + tnb[t];
  }
  __syncthreads();
  {                // H1 partials: de_w1 (128 x 96) — 128 cols x 4 segs(24) = 512
    int c = t >> 2, sg = t & 3, k0 = sg*24;
    float sm = 0.0f;
    for (int k = k0; k < k0+24; ++k) sm += L[A_NR+k]*dw1[c*96 + k];
    L[A_PART + t] = sm;
  }
  __syncthreads();
  if (t < 128) {
    int rb = t << 2;
    L[A_H1 + t] = L[A_PART+rb]+L[A_PART+rb+1]+L[A_PART+rb+2]+L[A_PART+rb+3] + db1[t];
  }
  __syncthreads();
  if (t < 128) {   // LN + GELU
    float mean = 0.0f; for (int e = 0; e < 128; ++e) mean += L[A_H1+e];
    mean *= (1.0f/128.0f);
    float var = 0.0f; for (int e = 0; e < 128; ++e) { float d = L[A_H1+e]-mean; var += d*d; }
    var *= (1.0f/128.0f);
    float y = (L[A_H1+t]-mean)*rsqrtf(var+1e-5f)*dg1[t] + dlb1[t];
    L[A_G1 + t] = gelu_f(y);
  }
  __syncthreads();
  if (t < 256) {   // H2 partials: de_w2 (64 x 128) — 64 cols x 4 segs(32)
    int c = t >> 2, sg = t & 3, k0 = sg*32;
    float sm = 0.0f;
    for (int k = k0; k < k0+32; ++k) sm += L[A_G1+k]*dw2[c*128 + k];
    L[A_PART + t] = sm;
  }
  __syncthreads();
  if (t < 64) {
    int rb = t << 2;
    L[A_H2 + t] = L[A_PART+rb]+L[A_PART+rb+1]+L[A_PART+rb+2]+L[A_PART+rb+3] + db2[t];
  }
  __syncthreads();
  if (t < 64) {
    float mean = 0.0f; for (int e = 0; e < 64; ++e) mean += L[A_H2+e];
    mean *= (1.0f/64.0f);
    float var = 0.0f; for (int e = 0; e < 64; ++e) { float d = L[A_H2+e]-mean; var += d*d; }
    var *= (1.0f/64.0f);
    ws[WS_DEA + s*ND + t] = (L[A_H2+t]-mean)*rsqrtf(var+1e-5f)*dg2[t] + dlb2[t];
  }
}

// --------------------------------------------------------- k4: one GNN layer
#define K4_RPB 4
#define K4_BPB 90   // ceil(358/4)

__global__ void __launch_bounds__(256)
k4_gnn(float* __restrict__ ws, int inoff, int outoff,
       const float* __restrict__ w, const float* __restrict__ bb,
       const float* __restrict__ g, const float* __restrict__ beta)
{
  __shared__ __align__(16) float nrow[K4_RPB][64];
  __shared__ float lg[K4_RPB][NNODES];
  __shared__ float pbl[K4_RPB][NNODES];
  __shared__ float aggp[4][K4_RPB][64];
  __shared__ float aggb[K4_RPB][64];
  __shared__ float prj[K4_RPB][64];
  int blk = blockIdx.x, t = threadIdx.x;
  int b = blk / K4_BPB;
  int n0 = (blk - b*K4_BPB)*K4_RPB;
  int nrows = NNODES - n0; if (nrows > K4_RPB) nrows = K4_RPB;
  {
    int r = t >> 6, d = t & 63;
    nrow[r][d] = (r < nrows)
      ? ws[inoff + ((size_t)(b*NNODES) + n0 + r)*ND + d] : 0.0f;
  }
  __syncthreads();
  const float* deb = ws + inoff + (size_t)b*NNODES*ND;
  for (int m = t; m < NNODES; m += 256) {
    const float* dr = deb + (size_t)m*ND;
    float s0=0.f, s1=0.f, s2=0.f, s3=0.f;
    #pragma unroll
    for (int d0 = 0; d0 < 64; d0 += 4) {
      float4 dv = *(const float4*)&dr[d0];
      float4 n0v = *(const float4*)&nrow[0][d0];
      float4 n1v = *(const float4*)&nrow[1][d0];
      float4 n2v = *(const float4*)&nrow[2][d0];
      float4 n3v = *(const float4*)&nrow[3][d0];
      s0 += dv.x*n0v.x + dv.y*n0v.y + dv.z*n0v.z + dv.w*n0v.w;
      s1 += dv.x*n1v.x + dv.y*n1v.y + dv.z*n1v.z + dv.w*n1v.w;
      s2 += dv.x*n2v.x + dv.y*n2v.y + dv.z*n2v.z + dv.w*n2v.w;
      s3 += dv.x*n3v.x + dv.y*n3v.y + dv.z*n3v.z + dv.w*n3v.w;
    }
    lg[0][m] = s0*5.0f;
    lg[1][m] = s1*5.0f;
    lg[2][m] = s2*5.0f;
    lg[3][m] = s3*5.0f;
  }
  __syncthreads();
  int wv = t >> 6, lane = t & 63;
  {  // per-wave register softmax of row wv -> pbl[wv][.] (normalized)
    const float* lgr = lg[wv];
    float vals[6];
    #pragma unroll
    for (int j = 0; j < 6; ++j) {
      int m = lane + 64*j;
      vals[j] = (m < NNODES) ? lgr[m] : -1e30f;
    }
    float mx = vals[0];
    #pragma unroll
    for (int j = 1; j < 6; ++j) mx = fmaxf(mx, vals[j]);
    #pragma unroll
    for (int o = 32; o; o >>= 1) mx = fmaxf(mx, __shfl_xor(mx, o, 64));
    float M = mx;
    float ls = 0.0f;
    #pragma unroll
    for (int j = 0; j < 6; ++j) ls += __expf(vals[j] - M);
    #pragma unroll
    for (int o = 32; o; o >>= 1) ls += __shfl_xor(ls, o, 64);
    float inv = 1.0f/ls;
    #pragma unroll
    for (int j = 0; j < 6; ++j) {
      int m = lane + 64*j;
      if (m < NNODES) pbl[wv][m] = __expf(vals[j] - M)*inv;
    }
  }
  __syncthreads();
  {  // agg partials: wave wv handles m == wv (mod 4); d = lane (coalesced)
    int d = lane;
    float a0=0.f, a1=0.f, a2=0.f, a3=0.f;
    for (int m = wv; m < NNODES; m += 4) {
      float dv = deb[(size_t)m*ND + d];
      a0 += pbl[0][m]*dv;
      a1 += pbl[1][m]*dv;
      a2 += pbl[2][m]*dv;
      a3 += pbl[3][m]*dv;
    }
    aggp[wv][0][d] = a0;
    aggp[wv][1][d] = a1;
    aggp[wv][2][d] = a2;
    aggp[wv][3][d] = a3;
  }
  __syncthreads();
  {
    int r = t >> 6, d = t & 63;
    aggb[r][d] = aggp[0][r][d]+aggp[1][r][d]+aggp[2][r][d]+aggp[3][r][d];
  }
  __syncthreads();
  {  // proj: 4 rows x 64 cols = 256 threads
    int r = t >> 6, c = t & 63;
    float sm = 0.0f;
    for (int d = 0; d < 64; ++d) sm += aggb[r][d]*w[c*64 + d];
    prj[r][c] = sm + bb[c];
  }
  __syncthreads();
  {  // LN + GELU + residual, 4 rows in parallel
    int r = t >> 6, c = t & 63;
    float mean = 0.0f; for (int e = 0; e < 64; ++e) mean += prj[r][e];
    mean *= (1.0f/64.0f);
    float var = 0.0f; for (int e = 0; e < 64; ++e) { float d = prj[r][e]-mean; var += d*d; }
    var *= (1.0f/64.0f);
    float y = (prj[r][c]-mean)*rsqrtf(var+1e-5f)*g[c] + beta[c];
    if (r < nrows)
      ws[outoff + ((size_t)(b*NNODES) + n0 + r)*ND + c] = gelu_f(y) + nrow[r][c];
  }
}

// ----------------------------------------------- k5: dynamic adj + top-k
#define K5_RPB 4
#define K5_BPH 90   // ceil(358/4)

__global__ void __launch_bounds__(256)
k5_dyn4(const float* __restrict__ ws, const float* __restrict__ se2,
        const float* __restrict__ temp, float* __restrict__ outdyn)
{
  __shared__ float den[K5_RPB][64];
  __shared__ float lg[K5_RPB][NNODES];
  int blk = blockIdx.x, t = threadIdx.x;
  int bh = blk / K5_BPH;              // 0..31  (b*4 + h)
  int n0 = (blk - bh*K5_BPH)*K5_RPB;  // 0,4,...,356
  int h = bh & 3, b = bh >> 2;
  int nrows = NNODES - n0; if (nrows > K5_RPB) nrows = K5_RPB;
  if (t < K5_RPB*64) {
    int r = t >> 6, d = t & 63;
    den[r][d] = (r < nrows)
      ? ws[WS_DEA + ((size_t)(b*NNODES) + n0 + r)*ND + d] : 0.0f;
  }
  __syncthreads();
  float tau = fminf(fmaxf(temp[h], 0.1f), 2.0f);
  const float* sp = se2 + (size_t)h*64*NNODES;
  float itau = 1.0f/tau;
  for (int m = t; m < NNODES; m += 256) {
    float s0=0.f, s1=0.f, s2=0.f, s3=0.f;
    for (int d = 0; d < 64; ++d) {
      float wv_ = sp[d*NNODES + m];
      s0 += den[0][d]*wv_;
      s1 += den[1][d]*wv_;
      s2 += den[2][d]*wv_;
      s3 += den[3][d]*wv_;
    }
    lg[0][m] = fmaxf(s0, 0.0f)*itau;
    lg[1][m] = fmaxf(s1, 0.0f)*itau;
    lg[2][m] = fmaxf(s2, 0.0f)*itau;
    lg[3][m] = fmaxf(s3, 0.0f)*itau;
  }
  __syncthreads();
  int wv = t >> 6;
  if (wv < nrows)
    wave_topk_row(lg[wv], outdyn + ((size_t)bh*NNODES + n0 + wv)*NNODES);
}

// ---------------------------------- k6: fusion + edge encoder + final adj
__global__ void __launch_bounds__(256)
k6_fuse(const float* __restrict__ ws, const float* __restrict__ outstat,
        const float* __restrict__ outdyn,
        const float* __restrict__ gfw, const float* __restrict__ gfb,
        const float* __restrict__ ew1, const float* __restrict__ eb1,
        const float* __restrict__ elg, const float* __restrict__ elb,
        const float* __restrict__ ew2, const float* __restrict__ eb2,
        const float* __restrict__ ew3, const float* __restrict__ eb3,
        float* __restrict__ outfin)
{
  __shared__ float sw1[64], sb1[16], slg[16], slb[16], sw2[128], sb2[8], sw3[8], sb3[1], sfw[4];
  int blk = blockIdx.x, t = threadIdx.x;
  int b = blk / NNODES, n = blk - b*NNODES;
  if (t < 64)  sw1[t] = ew1[t];
  if (t < 16)  { sb1[t] = eb1[t]; slg[t] = elg[t]; slb[t] = elb[t]; }
  if (t < 128) sw2[t] = ew2[t];
  if (t < 8)   { sb2[t] = eb2[t]; sw3[t] = ew3[t]; }
  if (t == 0)  sb3[0] = eb3[0];
  if (t < 4) {
    const float* pm = ws + WS_PRM + (size_t)blk*DIM;
    float sm = gfb[t];
    for (int e = 0; e < DIM; ++e) sm += pm[e]*gfw[t*DIM + e];
    sfw[t] = 1.0f/(1.0f+__expf(-sm));
  }
  __syncthreads();
  size_t srow = (size_t)n*NNODES;
  for (int m = t; m < NNODES; m += 256) {
    float fu[4]; float mn = 0.0f;
    #pragma unroll
    for (int hh = 0; hh < 4; ++hh) {
      float sv = outstat[(size_t)hh*NN2 + srow + m];
      float dv = outdyn[((size_t)(b*4+hh)*NNODES + n)*NNODES + m];
      float f = (1.0f - sfw[hh])*sv + sfw[hh]*dv;
      fu[hh] = f; mn += f;
    }
    mn *= 0.25f;
    float h1[16]; float m1 = 0.0f;
    #pragma unroll
    for (int j = 0; j < 16; ++j) {
      float sm = sb1[j];
      #pragma unroll
      for (int c = 0; c < 4; ++c) sm += fu[c]*sw1[j*4+c];
      h1[j] = sm; m1 += sm;
    }
    m1 *= (1.0f/16.0f);
    float v1 = 0.0f;
    #pragma unroll
    for (int j = 0; j < 16; ++j) { float d = h1[j]-m1; v1 += d*d; }
    float is1 = rsqrtf(v1*(1.0f/16.0f) + 1e-5f);
    #pragma unroll
    for (int j = 0; j < 16; ++j) h1[j] = gelu_f((h1[j]-m1)*is1*slg[j] + slb[j]);
    float h2[8];
    #pragma unroll
    for (int i = 0; i < 8; ++i) {
      float sm = sb2[i];
      #pragma unroll
      for (int j = 0; j < 16; ++j) sm += h1[j]*sw2[i*16+j];
      h2[i] = gelu_f(sm);
    }
    float ewv = sb3[0];
    #pragma unroll
    for (int i = 0; i < 8; ++i) ewv += h2[i]*sw3[i];
    float fin = (1.0f/(1.0f+__expf(-ewv)))*mn;
    outfin[(size_t)b*NN2 + srow + m] = fin;
  }
}

// ------------------------------------------------------------- launch
extern "C" void kernel_launch(void* const* d_in, const int* in_sizes, int n_in,
                              void* d_out, int out_size, void* d_ws, size_t ws_size,
                              hipStream_t stream)
{
  const float* pf   = (const float*)d_in[0];
  const float* se2  = (const float*)d_in[1];
  const float* le1  = (const float*)d_in[2];
  const float* le2  = (const float*)d_in[3];
  const float* ge1  = (const float*)d_in[4];
  const float* ge2  = (const float*)d_in[5];
  const float* temp = (const float*)d_in[6];
  const float* wi   = (const float*)d_in[7];
  const float* inb  = (const float*)d_in[8];
  const float* wo   = (const float*)d_in[9];
  const float* bo   = (const float*)d_in[10];
  const float* tng  = (const float*)d_in[11];
  const float* tnb  = (const float*)d_in[12];
  const float* dw1  = (const float*)d_in[13];
  const float* db1  = (const float*)d_in[14];
  const float* dg1  = (const float*)d_in[15];
  const float* dlb1 = (const float*)d_in[16];
  const float* dw2  = (const float*)d_in[17];
  const float* db2  = (const float*)d_in[18];
  const float* dg2  = (const float*)d_in[19];
  const float* dlb2 = (const float*)d_in[20];
  const float* pos  = (const float*)d_in[21];
  const float* g1w  = (const float*)d_in[22];
  const float* g1b  = (const float*)d_in[23];
  const float* g1g  = (const float*)d_in[24];
  const float* g1be = (const float*)d_in[25];
  const float* g2w  = (const float*)d_in[26];
  const float* g2b  = (const float*)d_in[27];
  const float* g2g  = (const float*)d_in[28];
  const float* g2be = (const float*)d_in[29];
  const float* gfw  = (const float*)d_in[30];
  const float* gfb  = (const float*)d_in[31];
  const float* ew1  = (const float*)d_in[32];
  const float* eb1  = (const float*)d_in[33];
  const float* elg  = (const float*)d_in[34];
  const float* elb  = (const float*)d_in[35];
  const float* ew2  = (const float*)d_in[36];
  const float* eb2  = (const float*)d_in[37];
  const float* ew3  = (const float*)d_in[38];
  const float* eb3  = (const float*)d_in[39];
  float* ws = (float*)d_ws;
  float* out = (float*)d_out;
  float* outfin  = out;                            // (B,N,N)
  float* outstat = out + (size_t)NB*NN2;           // (H,N,N)
  float* outdyn  = out + (size_t)(NB+NH)*NN2;      // (B,H,N,N)

  k0_setup<<<1, 256, 0, stream>>>(wi, wo, bo, pos, ws);
  k1_static4<<<NH*K1_BPH, 256, 0, stream>>>(le1, le2, ge1, ge2, temp, outstat);
  k2a_fused<<<SEQ, 512, 0, stream>>>(pf, pos, inb, ws, wo, bo, tng, tnb,
                                     dw1, db1, dg1, dlb1, dw2, db2, dg2, dlb2);
  k4_gnn<<<NB*K4_BPB, 256, 0, stream>>>(ws, WS_DEA, WS_DEB, g1w, g1b, g1g, g1be);
  k4_gnn<<<NB*K4_BPB, 256, 0, stream>>>(ws, WS_DEB, WS_DEA, g2w, g2b, g2g, g2be);
  k5_dyn4<<<NB*NH*K5_BPH, 256, 0, stream>>>(ws, se2, temp, outdyn);
  k6_fuse<<<SEQ, 256, 0, stream>>>(ws, outstat, outdyn, gfw, gfb,
                                   ew1, eb1, elg, elb, ew2, eb2, ew3, eb3, outfin);
}

// Round 11
// 915.574 us; speedup vs baseline: 1.0803x; 1.0278x over previous
//
#include <hip/hip_runtime.h>
#include <math.h>

#define NNODES 358
#define NN2 (358*358)
#define DIM 96
#define PP 72
#define ND 64
#define NB 8
#define NH 4
#define SEQ (NB*NNODES)

// ---- workspace layout (float offsets) ----
#define WS_WT2   0            // 4*96*72: per-head transposed in_proj (k-major [h][k][72])
#define WS_WBAR  27648        // 96
#define WS_BBAR  27744        // 1
#define WS_POSB  27748        // 96: column-mean of pos
#define WS_PRM   27848        // SEQ*96
#define WS_DEA   302792       // SEQ*64
#define WS_DEB   486088       // SEQ*64  (ends 669384)

__device__ __forceinline__ float gelu_f(float y) {
  return 0.5f*y*(1.0f+erff(y*0.70710678118654752440f));
}

// -------- per-wave register softmax+top-10 over one row of 358 logits -------
__device__ __forceinline__ void wave_topk_row(const float* __restrict__ lgr,
                                              float* __restrict__ orow)
{
  int lane = threadIdx.x & 63;
  float vals[6];
  #pragma unroll
  for (int j = 0; j < 6; ++j) {
    int m = lane + 64*j;
    vals[j] = (m < NNODES) ? lgr[m] : -1e30f;
  }
  float mx = vals[0];
  #pragma unroll
  for (int j = 1; j < 6; ++j) mx = fmaxf(mx, vals[j]);
  #pragma unroll
  for (int o = 32; o; o >>= 1) mx = fmaxf(mx, __shfl_xor(mx, o, 64));
  float M = mx;
  float ls = 0.0f;
  #pragma unroll
  for (int j = 0; j < 6; ++j) ls += __expf(vals[j] - M);   // OOB -> exp(-big)=0
  #pragma unroll
  for (int o = 32; o; o >>= 1) ls += __shfl_xor(ls, o, 64);
  float invS = 1.0f/ls;
  float outv[6] = {0.f, 0.f, 0.f, 0.f, 0.f, 0.f};
  float ss = 0.0f;
  for (int it = 0; it < 10; ++it) {
    float v = -1e30f; int idx = 0x7fffffff;
    #pragma unroll
    for (int j = 0; j < 6; ++j) {
      if (vals[j] > v) { v = vals[j]; idx = lane + 64*j; }
    }
    #pragma unroll
    for (int o = 1; o < 64; o <<= 1) {
      float ov = __shfl_xor(v, o, 64);
      int oi = __shfl_xor(idx, o, 64);
      if (ov > v || (ov == v && oi < idx)) { v = ov; idx = oi; }
    }
    ss += __expf(v - M);
    #pragma unroll
    for (int j = 0; j < 6; ++j)
      if (lane + 64*j == idx) { outv[j] = __expf(v - M); vals[j] = -1e30f; }
  }
  float dn = 1.0f/(ss*invS + 1e-8f);
  #pragma unroll
  for (int j = 0; j < 6; ++j) {
    int m = lane + 64*j;
    if (m < NNODES) orow[m] = outv[j]*invS*dn;
  }
}

// ---------------------------------------------------------------- k0: setup
__global__ void k0_setup(const float* __restrict__ wi, const float* __restrict__ wo,
                         const float* __restrict__ bo, const float* __restrict__ pos,
                         float* __restrict__ ws)
{
  int t = threadIdx.x;
  for (int idx = t; idx < 4*96*72; idx += 256) {
    int h = idx / (96*72);
    int r = idx - h*96*72;
    int k = r / 72;
    int gc = r - k*72;
    int g = gc / 24, c = gc - g*24;
    ws[WS_WT2 + idx] = wi[(size_t)(g*96 + h*24 + c)*96 + k];
  }
  if (t < 96) {
    float sm = 0.0f;
    for (int d = 0; d < 96; ++d) sm += wo[d*96 + t];
    ws[WS_WBAR + t] = sm*(1.0f/96.0f);
    float ps = 0.0f;
    for (int p = 0; p < PP; ++p) ps += pos[p*96 + t];
    ws[WS_POSB + t] = ps*(1.0f/72.0f);
  }
  if (t == 0) {
    float sm = 0.0f;
    for (int d = 0; d < 96; ++d) sm += bo[d];
    ws[WS_BBAR] = sm*(1.0f/96.0f);
  }
}

// --------------------------------------------------- k1: static adjacencies
#define K1_RPB 4
#define K1_BPH 90   // ceil(358/4)

__global__ void __launch_bounds__(256)
k1_static4(const float* __restrict__ le1, const float* __restrict__ le2,
           const float* __restrict__ ge1, const float* __restrict__ ge2,
           const float* __restrict__ temp, float* __restrict__ outstat)
{
  __shared__ float e1s[K1_RPB][64];
  __shared__ float lg[K1_RPB][NNODES];
  int blk = blockIdx.x, t = threadIdx.x;
  int h = blk / K1_BPH;
  int n0 = (blk - h*K1_BPH)*K1_RPB;
  int nrows = NNODES - n0; if (nrows > K1_RPB) nrows = K1_RPB;
  int kd; const float* e2p; float tau;
  if (h < 2) {
    kd = 32;
    e2p = le2 + (size_t)h*32*NNODES;
    tau = fminf(fmaxf(temp[h]*2.0f, 0.1f), 5.0f);
  } else {
    kd = 64;
    e2p = ge2 + (size_t)(h-2)*64*NNODES;
    tau = fminf(fmaxf(temp[h]*0.5f, 0.1f), 2.0f);
  }
  {
    int r = t >> 6, k = t & 63;
    float v = 0.0f;
    if (r < nrows && k < kd)
      v = (h < 2) ? le1[((size_t)h*NNODES + n0 + r)*32 + k]
                  : ge1[((size_t)(h-2)*NNODES + n0 + r)*64 + k];
    e1s[r][k] = v;
  }
  __syncthreads();
  float itau = 1.0f/tau;
  for (int m = t; m < NNODES; m += 256) {
    float s0=0.f, s1=0.f, s2=0.f, s3=0.f;
    for (int k = 0; k < kd; ++k) {
      float ev = e2p[k*NNODES + m];
      s0 += e1s[0][k]*ev;
      s1 += e1s[1][k]*ev;
      s2 += e1s[2][k]*ev;
      s3 += e1s[3][k]*ev;
    }
    lg[0][m] = fmaxf(s0, 0.0f)*itau;
    lg[1][m] = fmaxf(s1, 0.0f)*itau;
    lg[2][m] = fmaxf(s2, 0.0f)*itau;
    lg[3][m] = fmaxf(s3, 0.0f)*itau;
  }
  __syncthreads();
  int wv = t >> 6;
  if (wv < nrows)
    wave_topk_row(lg[wv], outstat + ((size_t)h*NNODES + n0 + wv)*NNODES);
}

// --------------------------------------- k2a_fused: per-s attention (4 heads)
//                                          + node epilogue + dynamic encoder
// FINAL (= round-8 exact): 512 threads, __launch_bounds__(512, 4) -> VGPR cap
// 64, 2 blocks/CU = 16 waves/CU. Measured optimum across the full config space
// (r1-r10): 16 waves + ~180MB cold spill (533us) beats every low-spill
// low-wave config (594/666/732/791us) and every retile (r9 bigger tiles:
// -60% bank conflicts but +70MB spill, net -57us; r10 merged softmax: -12us).
// k2a is LDS-read-BW bound (~86 B/cyc/CU = ds_read_b128 ceiling) with tile
// sizes pinned by the register cap — structural ceiling for this algorithm.
#define A_XS    0      // X' 72x100 (QKV input); after head loop: O 72x100
#define A_WH    7200   // W_h 96x72 k-major (6912); aliased by S after QKV
#define A_SS    7200   // S 72x76 (alias of A_WH)
#define A_WB    7200   // --- tail scratch (S dead) ---
#define A_LIMP  7296
#define A_IMP   7368
#define A_WSUM  7440
#define A_NB    7536
#define A_NR    7632
#define A_H1    7728
#define A_G1    7856
#define A_H2    7984   // ends 8048
#define A_PART  12672  // 512
#define A_PART2 13184  // 288
#define A_QH    14112  // Q 72x28
#define A_KT    16128  // K^T 24x76
#define A_VT    17952  // V^T 24x76
#define A_PRM   19776  // 96 (survives head loop)
#define A_TOT   19872

__global__ void __launch_bounds__(512, 4)
k2a_fused(const float* __restrict__ pf, const float* __restrict__ pos,
          const float* __restrict__ inb, float* __restrict__ ws,
          const float* __restrict__ wo, const float* __restrict__ bo,
          const float* __restrict__ tng, const float* __restrict__ tnb,
          const float* __restrict__ dw1, const float* __restrict__ db1,
          const float* __restrict__ dg1, const float* __restrict__ dlb1,
          const float* __restrict__ dw2, const float* __restrict__ db2,
          const float* __restrict__ dg2, const float* __restrict__ dlb2)
{
  __shared__ __align__(16) float L[A_TOT];
  int t = threadIdx.x;
  size_t s = blockIdx.x;
  const float* prp = pf + s*(PP*DIM);
  // ---- X = pf + pos -> LDS (stride 100), single fused pass
  for (int idx = t; idx < 1728; idx += 512) {
    float4 v = ((const float4*)prp)[idx];
    float4 q = ((const float4*)pos)[idx];
    v.x += q.x; v.y += q.y; v.z += q.z; v.w += q.w;
    int p = idx / 24, e4 = idx - p*24;
    *(float4*)&L[A_XS + p*100 + e4*4] = v;
  }
  __syncthreads();
  if (t < DIM) {   // pf.mean over P == colmean(X') - colmean(pos)
    float sm = 0.0f;
    for (int p = 0; p < PP; ++p) sm += L[A_XS + p*100 + t];
    sm = sm*(1.0f/72.0f) - ws[WS_POSB + t];
    L[A_PRM + t] = sm;
    ws[WS_PRM + s*DIM + t] = sm;       // k6 needs it
  }
  const float SC = 0.20412414523193150f;  // 1/sqrt(24)
  float4 oreg0, oreg1, oreg2, oreg3;       // per-head PV output (named -> regs)
  #pragma unroll
  for (int h = 0; h < NH; ++h) {
    __syncthreads();   // h=0: X/prm ready; h>0: prev PV done reading S (W aliases S)
    __builtin_amdgcn_sched_barrier(0);
    // ---- stage W_h (k-major [96][72]) into LDS: linear float4 copy
    const float4* wsrc = (const float4*)(ws + WS_WT2 + (size_t)h*6912);
    for (int idx = t; idx < 1728; idx += 512)
      *(float4*)&L[A_WH + idx*4] = wsrc[idx];
    __builtin_amdgcn_sched_barrier(0);
    __syncthreads();
    // ---- QKV: 24 row-tiles(3) x 18 col-tiles(4) = 432 threads, serial k=96
    if (t < 432) {
      int rt = t / 18, ct = t - rt*18;
      int p0 = rt*3, cc0 = ct*4;
      float acc[3][4];
      #pragma unroll
      for (int a = 0; a < 3; ++a)
        { acc[a][0]=0.f; acc[a][1]=0.f; acc[a][2]=0.f; acc[a][3]=0.f; }
      for (int k0 = 0; k0 < 96; k0 += 4) {
        float4 xv[3];
        #pragma unroll
        for (int a = 0; a < 3; ++a) xv[a] = *(const float4*)&L[A_XS + (p0+a)*100 + k0];
        float4 wv[4];
        #pragma unroll
        for (int kk = 0; kk < 4; ++kk) wv[kk] = *(const float4*)&L[A_WH + (k0+kk)*72 + cc0];
        #pragma unroll
        for (int kk = 0; kk < 4; ++kk) {
          #pragma unroll
          for (int a = 0; a < 3; ++a) {
            float xa = ((const float*)&xv[a])[kk];
            acc[a][0] += xa*wv[kk].x;
            acc[a][1] += xa*wv[kk].y;
            acc[a][2] += xa*wv[kk].z;
            acc[a][3] += xa*wv[kk].w;
          }
        }
      }
      int g = cc0 / 24;           // 0=q,1=k,2=v (tile never straddles: 4|24)
      int ch = cc0 - g*24;
      #pragma unroll
      for (int c = 0; c < 4; ++c) {
        float bias = inb[g*96 + h*24 + ch + c];
        #pragma unroll
        for (int a = 0; a < 3; ++a) {
          float v = acc[a][c] + bias;
          int p = p0 + a;
          if (g == 0)      L[A_QH + p*28 + ch + c] = v*SC;
          else if (g == 1) L[A_KT + (ch+c)*76 + p] = v;
          else             L[A_VT + (ch+c)*76 + p] = v;
        }
      }
    }
    __syncthreads();                  // W dead from here: S aliases it
    for (int tile = t; tile < 648; tile += 512) {  // S = q k^T (2x4 tiles)
      int pt2 = tile / 18, jt2 = tile - pt2*18;
      int p0 = pt2*2, j0 = jt2*4;
      float a0=0,a1=0,a2=0,a3=0, c0=0,c1=0,c2=0,c3=0;
      #pragma unroll
      for (int d0 = 0; d0 < 24; d0 += 4) {
        float4 q0 = *(const float4*)&L[A_QH + p0*28 + d0];
        float4 q1 = *(const float4*)&L[A_QH + (p0+1)*28 + d0];
        #pragma unroll
        for (int dd = 0; dd < 4; ++dd) {
          float4 kv = *(const float4*)&L[A_KT + (d0+dd)*76 + j0];
          float qa = ((const float*)&q0)[dd];
          float qb = ((const float*)&q1)[dd];
          a0 += qa*kv.x; a1 += qa*kv.y; a2 += qa*kv.z; a3 += qa*kv.w;
          c0 += qb*kv.x; c1 += qb*kv.y; c2 += qb*kv.z; c3 += qb*kv.w;
        }
      }
      *(float4*)&L[A_SS + p0*76 + j0]     = make_float4(a0,a1,a2,a3);
      *(float4*)&L[A_SS + (p0+1)*76 + j0] = make_float4(c0,c1,c2,c3);
    }
    __syncthreads();
    if (t < 288) {                    // softmax pass1: segment max (72 rows x 4 segs)
      int r = t >> 2, sg = t & 3, j0 = sg*18;
      const float* row = &L[A_SS + r*76];
      float mx = row[j0];
      for (int j = j0+1; j < j0+18; ++j) mx = fmaxf(mx, row[j]);
      L[A_PART + t] = mx;
    }
    __syncthreads();
    if (t < 288) {                    // pass2: exp + segment sum (sum-norm folded into PV)
      int r = t >> 2, sg = t & 3, j0 = sg*18;
      int rb = r << 2;
      float M = fmaxf(fmaxf(L[A_PART+rb], L[A_PART+rb+1]),
                      fmaxf(L[A_PART+rb+2], L[A_PART+rb+3]));
      float* row = &L[A_SS + r*76];
      float sm = 0.0f;
      for (int j = j0; j < j0+18; ++j) { float e = __expf(row[j]-M); row[j] = e; sm += e; }
      L[A_PART2 + t] = sm;
    }
    __syncthreads();
    if (t < 432) {                    // PV: 1 row x 4 cols per thread
      int p = t / 6, dt = t - (t/6)*6;
      int d0 = dt*4, rb = p << 2;
      float S4 = L[A_PART2+rb]+L[A_PART2+rb+1]+L[A_PART2+rb+2]+L[A_PART2+rb+3];
      float inv = 1.0f/S4;
      float a0=0,a1=0,a2=0,a3=0;
      for (int j0 = 0; j0 < 72; j0 += 4) {
        float4 pv = *(const float4*)&L[A_SS + p*76 + j0];
        float4 v0 = *(const float4*)&L[A_VT + (d0+0)*76 + j0];
        float4 v1 = *(const float4*)&L[A_VT + (d0+1)*76 + j0];
        float4 v2 = *(const float4*)&L[A_VT + (d0+2)*76 + j0];
        float4 v3 = *(const float4*)&L[A_VT + (d0+3)*76 + j0];
        a0 += pv.x*v0.x + pv.y*v0.y + pv.z*v0.z + pv.w*v0.w;
        a1 += pv.x*v1.x + pv.y*v1.y + pv.z*v1.z + pv.w*v1.w;
        a2 += pv.x*v2.x + pv.y*v2.y + pv.z*v2.z + pv.w*v2.w;
        a3 += pv.x*v3.x + pv.y*v3.y + pv.z*v3.z + pv.w*v3.w;
      }
      float4 ov = make_float4(a0*inv, a1*inv, a2*inv, a3*inv);
      if (h == 0)      oreg0 = ov;
      else if (h == 1) oreg1 = ov;
      else if (h == 2) oreg2 = ov;
      else             oreg3 = ov;
    }
  }
  // ---- node epilogue; O overwrites dead X region, scratch aliases dead S
  __syncthreads();                    // last PV done reading S before WB/O writes
  if (t < 432) {
    int p = t / 6, dt = t - (t/6)*6;
    int d0 = dt*4;
    *(float4*)&L[A_XS + p*100 +  0 + d0] = oreg0;
    *(float4*)&L[A_XS + p*100 + 24 + d0] = oreg1;
    *(float4*)&L[A_XS + p*100 + 48 + d0] = oreg2;
    *(float4*)&L[A_XS + p*100 + 72 + d0] = oreg3;
  }
  if (t < 96) L[A_WB + t] = ws[WS_WBAR + t];
  __syncthreads();
  if (t < 288) {   // limp partials: att.mean(-1) == O . wbar (+bbar in combine)
    int r = t >> 2, sg = t & 3, e0 = sg*24;
    float sm = 0.0f;
    for (int e = e0; e < e0+24; ++e) sm += L[A_XS + r*100 + e]*L[A_WB + e];
    L[A_PART + t] = sm;
  }
  __syncthreads();
  if (t < 72) {
    int rb = t << 2;
    L[A_LIMP + t] = L[A_PART+rb]+L[A_PART+rb+1]+L[A_PART+rb+2]+L[A_PART+rb+3]
                  + ws[WS_BBAR];
  }
  __syncthreads();
  if (t < 72) {    // patch-importance softmax (small, serial)
    float mx = L[A_LIMP];
    for (int j = 1; j < 72; ++j) mx = fmaxf(mx, L[A_LIMP+j]);
    float sm = 0.0f;
    for (int j = 0; j < 72; ++j) sm += __expf(L[A_LIMP+j]-mx);
    L[A_IMP + t] = __expf(L[A_LIMP+t]-mx)/sm;
  }
  __syncthreads();
  if (t < 384) {   // wsum partials: (O * imp).sum over p
    int c = t >> 2, sg = t & 3, p0 = sg*18;
    float sm = 0.0f;
    for (int p = p0; p < p0+18; ++p) sm += L[A_IMP+p]*L[A_XS + p*100 + c];
    L[A_PART + t] = sm;
  }
  __syncthreads();
  if (t < 96) {
    int rb = t << 2;
    L[A_WSUM + t] = L[A_PART+rb]+L[A_PART+rb+1]+L[A_PART+rb+2]+L[A_PART+rb+3];
  }
  __syncthreads();
  if (t < 384) {   // NB partials: out_proj
    int c = t >> 2, sg = t & 3, e0 = sg*24;
    float sm = 0.0f;
    for (int e = e0; e < e0+24; ++e) sm += L[A_WSUM+e]*wo[c*96 + e];
    L[A_PART + t] = sm;
  }
  __syncthreads();
  if (t < 96) {
    int rb = t << 2;
    L[A_NB + t] = L[A_PART+rb]+L[A_PART+rb+1]+L[A_PART+rb+2]+L[A_PART+rb+3]
                + bo[t] + L[A_PRM + t];
  }
  __syncthreads();
  if (t < 96) {    // token LN
    float mean = 0.0f;
    for (int e = 0; e < 96; ++e) mean += L[A_NB+e];
    mean *= (1.0f/96.0f);
    float var = 0.0f;
    for (int e = 0; e < 96; ++e) { float d = L[A_NB+e]-mean; var += d*d; }
    var *= (1.0f/96.0f);
    L[A_NR + t] = (L[A_NB+t]-mean)*rsqrtf(var+1e-5f)*tng[t] + tnb[t];
  }
  __syncthreads();
  {                // H1 partials: de_w1 (128 x 96) — 128 cols x 4 segs(24) = 512
    int c = t >> 2, sg = t & 3, k0 = sg*24;
    float sm = 0.0f;
    for (int k = k0; k < k0+24; ++k) sm += L[A_NR+k]*dw1[c*96 + k];
    L[A_PART + t] = sm;
  }
  __syncthreads();
  if (t < 128) {
    int rb = t << 2;
    L[A_H1 + t] = L[A_PART+rb]+L[A_PART+rb+1]+L[A_PART+rb+2]+L[A_PART+rb+3] + db1[t];
  }
  __syncthreads();
  if (t < 128) {   // LN + GELU
    float mean = 0.0f; for (int e = 0; e < 128; ++e) mean += L[A_H1+e];
    mean *= (1.0f/128.0f);
    float var = 0.0f; for (int e = 0; e < 128; ++e) { float d = L[A_H1+e]-mean; var += d*d; }
    var *= (1.0f/128.0f);
    float y = (L[A_H1+t]-mean)*rsqrtf(var+1e-5f)*dg1[t] + dlb1[t];
    L[A_G1 + t] = gelu_f(y);
  }
  __syncthreads();
  if (t < 256) {   // H2 partials: de_w2 (64 x 128) — 64 cols x 4 segs(32)
    int c = t >> 2, sg = t & 3, k0 = sg*32;
    float sm = 0.0f;
    for (int k = k0; k < k0+32; ++k) sm += L[A_G1+k]*dw2[c*128 + k];
    L[A_PART + t] = sm;
  }
  __syncthreads();
  if (t < 64) {
    int rb = t << 2;
    L[A_H2 + t] = L[A_PART+rb]+L[A_PART+rb+1]+L[A_PART+rb+2]+L[A_PART+rb+3] + db2[t];
  }
  __syncthreads();
  if (t < 64) {
    float mean = 0.0f; for (int e = 0; e < 64; ++e) mean += L[A_H2+e];
    mean *= (1.0f/64.0f);
    float var = 0.0f; for (int e = 0; e < 64; ++e) { float d = L[A_H2+e]-mean; var += d*d; }
    var *= (1.0f/64.0f);
    ws[WS_DEA + s*ND + t] = (L[A_H2+t]-mean)*rsqrtf(var+1e-5f)*dg2[t] + dlb2[t];
  }
}

// --------------------------------------------------------- k4: one GNN layer
#define K4_RPB 4
#define K4_BPB 90   // ceil(358/4)

__global__ void __launch_bounds__(256)
k4_gnn(float* __restrict__ ws, int inoff, int outoff,
       const float* __restrict__ w, const float* __restrict__ bb,
       const float* __restrict__ g, const float* __restrict__ beta)
{
  __shared__ __align__(16) float nrow[K4_RPB][64];
  __shared__ float lg[K4_RPB][NNODES];
  __shared__ float pbl[K4_RPB][NNODES];
  __shared__ float aggp[4][K4_RPB][64];
  __shared__ float aggb[K4_RPB][64];
  __shared__ float prj[K4_RPB][64];
  int blk = blockIdx.x, t = threadIdx.x;
  int b = blk / K4_BPB;
  int n0 = (blk - b*K4_BPB)*K4_RPB;
  int nrows = NNODES - n0; if (nrows > K4_RPB) nrows = K4_RPB;
  {
    int r = t >> 6, d = t & 63;
    nrow[r][d] = (r < nrows)
      ? ws[inoff + ((size_t)(b*NNODES) + n0 + r)*ND + d] : 0.0f;
  }
  __syncthreads();
  const float* deb = ws + inoff + (size_t)b*NNODES*ND;
  for (int m = t; m < NNODES; m += 256) {
    const float* dr = deb + (size_t)m*ND;
    float s0=0.f, s1=0.f, s2=0.f, s3=0.f;
    #pragma unroll
    for (int d0 = 0; d0 < 64; d0 += 4) {
      float4 dv = *(const float4*)&dr[d0];
      float4 n0v = *(const float4*)&nrow[0][d0];
      float4 n1v = *(const float4*)&nrow[1][d0];
      float4 n2v = *(const float4*)&nrow[2][d0];
      float4 n3v = *(const float4*)&nrow[3][d0];
      s0 += dv.x*n0v.x + dv.y*n0v.y + dv.z*n0v.z + dv.w*n0v.w;
      s1 += dv.x*n1v.x + dv.y*n1v.y + dv.z*n1v.z + dv.w*n1v.w;
      s2 += dv.x*n2v.x + dv.y*n2v.y + dv.z*n2v.z + dv.w*n2v.w;
      s3 += dv.x*n3v.x + dv.y*n3v.y + dv.z*n3v.z + dv.w*n3v.w;
    }
    lg[0][m] = s0*5.0f;
    lg[1][m] = s1*5.0f;
    lg[2][m] = s2*5.0f;
    lg[3][m] = s3*5.0f;
  }
  __syncthreads();
  int wv = t >> 6, lane = t & 63;
  {  // per-wave register softmax of row wv -> pbl[wv][.] (normalized)
    const float* lgr = lg[wv];
    float vals[6];
    #pragma unroll
    for (int j = 0; j < 6; ++j) {
      int m = lane + 64*j;
      vals[j] = (m < NNODES) ? lgr[m] : -1e30f;
    }
    float mx = vals[0];
    #pragma unroll
    for (int j = 1; j < 6; ++j) mx = fmaxf(mx, vals[j]);
    #pragma unroll
    for (int o = 32; o; o >>= 1) mx = fmaxf(mx, __shfl_xor(mx, o, 64));
    float M = mx;
    float ls = 0.0f;
    #pragma unroll
    for (int j = 0; j < 6; ++j) ls += __expf(vals[j] - M);
    #pragma unroll
    for (int o = 32; o; o >>= 1) ls += __shfl_xor(ls, o, 64);
    float inv = 1.0f/ls;
    #pragma unroll
    for (int j = 0; j < 6; ++j) {
      int m = lane + 64*j;
      if (m < NNODES) pbl[wv][m] = __expf(vals[j] - M)*inv;
    }
  }
  __syncthreads();
  {  // agg partials: wave wv handles m == wv (mod 4); d = lane (coalesced)
    int d = lane;
    float a0=0.f, a1=0.f, a2=0.f, a3=0.f;
    for (int m = wv; m < NNODES; m += 4) {
      float dv = deb[(size_t)m*ND + d];
      a0 += pbl[0][m]*dv;
      a1 += pbl[1][m]*dv;
      a2 += pbl[2][m]*dv;
      a3 += pbl[3][m]*dv;
    }
    aggp[wv][0][d] = a0;
    aggp[wv][1][d] = a1;
    aggp[wv][2][d] = a2;
    aggp[wv][3][d] = a3;
  }
  __syncthreads();
  {
    int r = t >> 6, d = t & 63;
    aggb[r][d] = aggp[0][r][d]+aggp[1][r][d]+aggp[2][r][d]+aggp[3][r][d];
  }
  __syncthreads();
  {  // proj: 4 rows x 64 cols = 256 threads
    int r = t >> 6, c = t & 63;
    float sm = 0.0f;
    for (int d = 0; d < 64; ++d) sm += aggb[r][d]*w[c*64 + d];
    prj[r][c] = sm + bb[c];
  }
  __syncthreads();
  {  // LN + GELU + residual, 4 rows in parallel
    int r = t >> 6, c = t & 63;
    float mean = 0.0f; for (int e = 0; e < 64; ++e) mean += prj[r][e];
    mean *= (1.0f/64.0f);
    float var = 0.0f; for (int e = 0; e < 64; ++e) { float d = prj[r][e]-mean; var += d*d; }
    var *= (1.0f/64.0f);
    float y = (prj[r][c]-mean)*rsqrtf(var+1e-5f)*g[c] + beta[c];
    if (r < nrows)
      ws[outoff + ((size_t)(b*NNODES) + n0 + r)*ND + c] = gelu_f(y) + nrow[r][c];
  }
}

// ----------------------------------------------- k5: dynamic adj + top-k
#define K5_RPB 4
#define K5_BPH 90   // ceil(358/4)

__global__ void __launch_bounds__(256)
k5_dyn4(const float* __restrict__ ws, const float* __restrict__ se2,
        const float* __restrict__ temp, float* __restrict__ outdyn)
{
  __shared__ float den[K5_RPB][64];
  __shared__ float lg[K5_RPB][NNODES];
  int blk = blockIdx.x, t = threadIdx.x;
  int bh = blk / K5_BPH;              // 0..31  (b*4 + h)
  int n0 = (blk - bh*K5_BPH)*K5_RPB;  // 0,4,...,356
  int h = bh & 3, b = bh >> 2;
  int nrows = NNODES - n0; if (nrows > K5_RPB) nrows = K5_RPB;
  if (t < K5_RPB*64) {
    int r = t >> 6, d = t & 63;
    den[r][d] = (r < nrows)
      ? ws[WS_DEA + ((size_t)(b*NNODES) + n0 + r)*ND + d] : 0.0f;
  }
  __syncthreads();
  float tau = fminf(fmaxf(temp[h], 0.1f), 2.0f);
  const float* sp = se2 + (size_t)h*64*NNODES;
  float itau = 1.0f/tau;
  for (int m = t; m < NNODES; m += 256) {
    float s0=0.f, s1=0.f, s2=0.f, s3=0.f;
    for (int d = 0; d < 64; ++d) {
      float wv_ = sp[d*NNODES + m];
      s0 += den[0][d]*wv_;
      s1 += den[1][d]*wv_;
      s2 += den[2][d]*wv_;
      s3 += den[3][d]*wv_;
    }
    lg[0][m] = fmaxf(s0, 0.0f)*itau;
    lg[1][m] = fmaxf(s1, 0.0f)*itau;
    lg[2][m] = fmaxf(s2, 0.0f)*itau;
    lg[3][m] = fmaxf(s3, 0.0f)*itau;
  }
  __syncthreads();
  int wv = t >> 6;
  if (wv < nrows)
    wave_topk_row(lg[wv], outdyn + ((size_t)bh*NNODES + n0 + wv)*NNODES);
}

// ---------------------------------- k6: fusion + edge encoder + final adj
__global__ void __launch_bounds__(256)
k6_fuse(const float* __restrict__ ws, const float* __restrict__ outstat,
        const float* __restrict__ outdyn,
        const float* __restrict__ gfw, const float* __restrict__ gfb,
        const float* __restrict__ ew1, const float* __restrict__ eb1,
        const float* __restrict__ elg, const float* __restrict__ elb,
        const float* __restrict__ ew2, const float* __restrict__ eb2,
        const float* __restrict__ ew3, const float* __restrict__ eb3,
        float* __restrict__ outfin)
{
  __shared__ float sw1[64], sb1[16], slg[16], slb[16], sw2[128], sb2[8], sw3[8], sb3[1], sfw[4];
  int blk = blockIdx.x, t = threadIdx.x;
  int b = blk / NNODES, n = blk - b*NNODES;
  if (t < 64)  sw1[t] = ew1[t];
  if (t < 16)  { sb1[t] = eb1[t]; slg[t] = elg[t]; slb[t] = elb[t]; }
  if (t < 128) sw2[t] = ew2[t];
  if (t < 8)   { sb2[t] = eb2[t]; sw3[t] = ew3[t]; }
  if (t == 0)  sb3[0] = eb3[0];
  if (t < 4) {
    const float* pm = ws + WS_PRM + (size_t)blk*DIM;
    float sm = gfb[t];
    for (int e = 0; e < DIM; ++e) sm += pm[e]*gfw[t*DIM + e];
    sfw[t] = 1.0f/(1.0f+__expf(-sm));
  }
  __syncthreads();
  size_t srow = (size_t)n*NNODES;
  for (int m = t; m < NNODES; m += 256) {
    float fu[4]; float mn = 0.0f;
    #pragma unroll
    for (int hh = 0; hh < 4; ++hh) {
      float sv = outstat[(size_t)hh*NN2 + srow + m];
      float dv = outdyn[((size_t)(b*4+hh)*NNODES + n)*NNODES + m];
      float f = (1.0f - sfw[hh])*sv + sfw[hh]*dv;
      fu[hh] = f; mn += f;
    }
    mn *= 0.25f;
    float h1[16]; float m1 = 0.0f;
    #pragma unroll
    for (int j = 0; j < 16; ++j) {
      float sm = sb1[j];
      #pragma unroll
      for (int c = 0; c < 4; ++c) sm += fu[c]*sw1[j*4+c];
      h1[j] = sm; m1 += sm;
    }
    m1 *= (1.0f/16.0f);
    float v1 = 0.0f;
    #pragma unroll
    for (int j = 0; j < 16; ++j) { float d = h1[j]-m1; v1 += d*d; }
    float is1 = rsqrtf(v1*(1.0f/16.0f) + 1e-5f);
    #pragma unroll
    for (int j = 0; j < 16; ++j) h1[j] = gelu_f((h1[j]-m1)*is1*slg[j] + slb[j]);
    float h2[8];
    #pragma unroll
    for (int i = 0; i < 8; ++i) {
      float sm = sb2[i];
      #pragma unroll
      for (int j = 0; j < 16; ++j) sm += h1[j]*sw2[i*16+j];
      h2[i] = gelu_f(sm);
    }
    float ewv = sb3[0];
    #pragma unroll
    for (int i = 0; i < 8; ++i) ewv += h2[i]*sw3[i];
    float fin = (1.0f/(1.0f+__expf(-ewv)))*mn;
    outfin[(size_t)b*NN2 + srow + m] = fin;
  }
}

// ------------------------------------------------------------- launch
extern "C" void kernel_launch(void* const* d_in, const int* in_sizes, int n_in,
                              void* d_out, int out_size, void* d_ws, size_t ws_size,
                              hipStream_t stream)
{
  const float* pf   = (const float*)d_in[0];
  const float* se2  = (const float*)d_in[1];
  const float* le1  = (const float*)d_in[2];
  const float* le2  = (const float*)d_in[3];
  const float* ge1  = (const float*)d_in[4];
  const float* ge2  = (const float*)d_in[5];
  const float* temp = (const float*)d_in[6];
  const float* wi   = (const float*)d_in[7];
  const float* inb  = (const float*)d_in[8];
  const float* wo   = (const float*)d_in[9];
  const float* bo   = (const float*)d_in[10];
  const float* tng  = (const float*)d_in[11];
  const float* tnb  = (const float*)d_in[12];
  const float* dw1  = (const float*)d_in[13];
  const float* db1  = (const float*)d_in[14];
  const float* dg1  = (const float*)d_in[15];
  const float* dlb1 = (const float*)d_in[16];
  const float* dw2  = (const float*)d_in[17];
  const float* db2  = (const float*)d_in[18];
  const float* dg2  = (const float*)d_in[19];
  const float* dlb2 = (const float*)d_in[20];
  const float* pos  = (const float*)d_in[21];
  const float* g1w  = (const float*)d_in[22];
  const float* g1b  = (const float*)d_in[23];
  const float* g1g  = (const float*)d_in[24];
  const float* g1be = (const float*)d_in[25];
  const float* g2w  = (const float*)d_in[26];
  const float* g2b  = (const float*)d_in[27];
  const float* g2g  = (const float*)d_in[28];
  const float* g2be = (const float*)d_in[29];
  const float* gfw  = (const float*)d_in[30];
  const float* gfb  = (const float*)d_in[31];
  const float* ew1  = (const float*)d_in[32];
  const float* eb1  = (const float*)d_in[33];
  const float* elg  = (const float*)d_in[34];
  const float* elb  = (const float*)d_in[35];
  const float* ew2  = (const float*)d_in[36];
  const float* eb2  = (const float*)d_in[37];
  const float* ew3  = (const float*)d_in[38];
  const float* eb3  = (const float*)d_in[39];
  float* ws = (float*)d_ws;
  float* out = (float*)d_out;
  float* outfin  = out;                            // (B,N,N)
  float* outstat = out + (size_t)NB*NN2;           // (H,N,N)
  float* outdyn  = out + (size_t)(NB+NH)*NN2;      // (B,H,N,N)

  k0_setup<<<1, 256, 0, stream>>>(wi, wo, bo, pos, ws);
  k1_static4<<<NH*K1_BPH, 256, 0, stream>>>(le1, le2, ge1, ge2, temp, outstat);
  k2a_fused<<<SEQ, 512, 0, stream>>>(pf, pos, inb, ws, wo, bo, tng, tnb,
                                     dw1, db1, dg1, dlb1, dw2, db2, dg2, dlb2);
  k4_gnn<<<NB*K4_BPB, 256, 0, stream>>>(ws, WS_DEA, WS_DEB, g1w, g1b, g1g, g1be);
  k4_gnn<<<NB*K4_BPB, 256, 0, stream>>>(ws, WS_DEB, WS_DEA, g2w, g2b, g2g, g2be);
  k5_dyn4<<<NB*NH*K5_BPH, 256, 0, stream>>>(ws, se2, temp, outdyn);
  k6_fuse<<<SEQ, 256, 0, stream>>>(ws, outstat, outdyn, gfw, gfb,
                                   ew1, eb1, elg, elb, ew2, eb2, ew3, eb3, outfin);
}